// Round 10
// baseline (454.410 us; speedup 1.0000x reference)
//
#include <hip/hip_runtime.h>
#include <stdint.h>

// GCN: out = D^-1 A (relu(D^-1 A (feat W1) + b1) W2) + b2
//
// Path A (4 kernels, speculative-segment build, 2 lane-ops/edge in build):
//   k_transform1 : zq = pack16x2(feat @ W1)   [N] u32  (4 MB -> L2-resident)
//   k_build2     : each (block,bucket) owns a fixed 128-slot segment.
//                  per edge: LDS cur atomic -> scattered write. counts->scnt.
//   k_agg1_seg   : per bucket: one segment per wave; gather zq[src];
//                  ONE u64 LDS atomic/edge (qx|qy|count). h -> hq, deg.
//   k_agg2_seg   : same over hq; epilogue out = (sum/deg/S_H) @ W2 + b2.
// Path B = R9-proven pipeline (exact-CAP build + uint4 agg).  Path C = atomics.
//
// ws A words: recs[NBUCK*BGRID*SEGCAP] | scnt[NBUCK*BGRID] | deg[N] | zq[N] | hq[N]

#define BUCKBITS 9
#define NBUCK (1 << BUCKBITS)      // 512 dst buckets
#define LOCBITS 11
#define LOCN (1 << LOCBITS)        // 2048 nodes / bucket
#define SRCBITS 20
#define SRCMASK ((1u << SRCBITS) - 1u)
#define CAP 35072                  // path B exact-CAP
#define SEGCAP 128                 // path A per-(block,bucket) slots
#define BBLK 512
#define BGRID 512                  // build blocks (must stay 512: <<9 below)
#define AGGBLK 1024
#define NWAVES (AGGBLK >> 6)

#define S_Z 1024.0f
#define INV_S_Z (1.0f / 1024.0f)
#define B_Z 32.0f
#define S_H 2048.0f
#define INV_S_H (1.0f / 2048.0f)

__device__ __forceinline__ uint32_t q16(float v, float scale, float bias) {
    float f = (v + bias) * scale;
    f = fminf(fmaxf(f, 0.0f), 65535.0f);
    return (uint32_t)__builtin_rintf(f);
}

__device__ __forceinline__ unsigned long long pk1(uint32_t zv) {
    return (unsigned long long)(zv & 0xFFFFu) |
           ((unsigned long long)(zv >> 16) << 27) | (1ull << 54);
}
__device__ __forceinline__ unsigned long long pk2(uint32_t hv) {
    return (unsigned long long)(hv & 0xFFFFu) |
           ((unsigned long long)(hv >> 16) << 32);
}

__global__ void k_transform1(const float* __restrict__ feat,
                             const float* __restrict__ W1,
                             uint32_t* __restrict__ zq, int N) {
    int i = blockIdx.x * blockDim.x + threadIdx.x;
    if (i >= N) return;
    float f0 = feat[3 * i + 0];
    float f1 = feat[3 * i + 1];
    float f2 = feat[3 * i + 2];
    float zx = f0 * W1[0] + f1 * W1[2] + f2 * W1[4];
    float zy = f0 * W1[1] + f1 * W1[3] + f2 * W1[5];
    zq[i] = q16(zx, S_Z, B_Z) | (q16(zy, S_Z, B_Z) << 16);
}

// ---------- Path A: speculative-segment build (2 lane-ops/edge) ----------
__global__ __launch_bounds__(BBLK) void k_build2(const int* __restrict__ src,
                                                 const int* __restrict__ dst,
                                                 uint32_t* __restrict__ scnt,
                                                 uint32_t* __restrict__ recs, int E) {
    __shared__ uint32_t cur[NBUCK];
    int blk = blockIdx.x;
    for (int i = threadIdx.x; i < NBUCK; i += blockDim.x) cur[i] = 0u;
    __syncthreads();

    int chunk = (((E + BGRID - 1) / BGRID) + 3) & ~3;
    int beg = blk * chunk;
    int end = min(E, beg + chunk);
    int cnt = end - beg;
    if (cnt < 0) cnt = 0;
    int n4 = cnt >> 2;

    const int4* d4 = reinterpret_cast<const int4*>(dst + beg);
    const int4* s4 = reinterpret_cast<const int4*>(src + beg);
    for (int j = threadIdx.x; j < n4; j += blockDim.x) {
        int4 d = d4[j];
        int4 s = s4[j];
        int dd[4] = {d.x, d.y, d.z, d.w};
        int ss[4] = {s.x, s.y, s.z, s.w};
#pragma unroll
        for (int q = 0; q < 4; ++q) {
            unsigned dv = (unsigned)dd[q];
            unsigned b = dv >> LOCBITS;
            unsigned loc = dv & (LOCN - 1u);
            unsigned pos = atomicAdd(&cur[b], 1u);
            if (pos < SEGCAP)
                recs[(((size_t)b << 9) + blk) * SEGCAP + pos] =
                    (loc << SRCBITS) | (unsigned)ss[q];
        }
    }
    for (int e = beg + (n4 << 2) + threadIdx.x; e < end; e += blockDim.x) {
        unsigned dv = (unsigned)dst[e];
        unsigned b = dv >> LOCBITS;
        unsigned loc = dv & (LOCN - 1u);
        unsigned pos = atomicAdd(&cur[b], 1u);
        if (pos < SEGCAP)
            recs[(((size_t)b << 9) + blk) * SEGCAP + pos] =
                (loc << SRCBITS) | (unsigned)src[e];
    }
    __syncthreads();
    for (int b = threadIdx.x; b < NBUCK; b += blockDim.x)
        scnt[(size_t)b * BGRID + blk] = min(cur[b], (uint32_t)SEGCAP);
}

// layer-1 aggregation, segment-per-wave
__global__ __launch_bounds__(AGGBLK) void k_agg1_seg(const uint32_t* __restrict__ recs,
                                                     const uint32_t* __restrict__ scnt,
                                                     const uint32_t* __restrict__ zq,
                                                     const float* __restrict__ b1,
                                                     float* __restrict__ deg,
                                                     uint32_t* __restrict__ hq, int N) {
    __shared__ unsigned long long acc[LOCN];   // 16 KB
    __shared__ uint32_t scl[BGRID];            // 2 KB
    int b = blockIdx.x;
    for (int i = threadIdx.x; i < LOCN; i += blockDim.x) acc[i] = 0ull;
    for (int i = threadIdx.x; i < BGRID; i += blockDim.x)
        scl[i] = scnt[(size_t)b * BGRID + i];
    __syncthreads();
    int wave = threadIdx.x >> 6;
    int lane = threadIdx.x & 63;
    const uint32_t* rb = recs + (((size_t)b << 9) * SEGCAP);
    for (int s = wave; s < BGRID; s += NWAVES) {
        uint32_t c = scl[s];
        const uint32_t* rs = rb + (size_t)s * SEGCAP;
        for (uint32_t i = lane; i < c; i += 64) {
            uint32_t rec = rs[i];
            uint32_t zv = zq[rec & SRCMASK];
            atomicAdd(&acc[rec >> SRCBITS], pk1(zv));
        }
    }
    __syncthreads();
    float b10 = b1[0], b11 = b1[1];
    int base = b << LOCBITS;
    for (int i = threadIdx.x; i < LOCN; i += blockDim.x) {
        int n = base + i;
        if (n >= N) break;
        unsigned long long s = acc[i];
        float d = (float)(uint32_t)(s >> 54);
        float di = d > 0.0f ? 1.0f / d : 0.0f;
        float sqx = (float)(uint32_t)(s & 0x7FFFFFFull);
        float sqy = (float)(uint32_t)((s >> 27) & 0x7FFFFFFull);
        float mx = (sqx * INV_S_Z - B_Z * d) * di;
        float my = (sqy * INV_S_Z - B_Z * d) * di;
        float h0 = fmaxf(mx + b10, 0.0f);
        float h1 = fmaxf(my + b11, 0.0f);
        deg[n] = d;
        hq[n] = q16(h0, S_H, 0.0f) | (q16(h1, S_H, 0.0f) << 16);
    }
}

// layer-2 aggregation, segment-per-wave
__global__ __launch_bounds__(AGGBLK) void k_agg2_seg(const uint32_t* __restrict__ recs,
                                                     const uint32_t* __restrict__ scnt,
                                                     const uint32_t* __restrict__ hq,
                                                     const float* __restrict__ W2,
                                                     const float* __restrict__ b2,
                                                     const float* __restrict__ deg,
                                                     float* __restrict__ out, int N) {
    __shared__ unsigned long long acc[LOCN];   // 16 KB
    __shared__ uint32_t scl[BGRID];            // 2 KB
    int b = blockIdx.x;
    for (int i = threadIdx.x; i < LOCN; i += blockDim.x) acc[i] = 0ull;
    for (int i = threadIdx.x; i < BGRID; i += blockDim.x)
        scl[i] = scnt[(size_t)b * BGRID + i];
    __syncthreads();
    int wave = threadIdx.x >> 6;
    int lane = threadIdx.x & 63;
    const uint32_t* rb = recs + (((size_t)b << 9) * SEGCAP);
    for (int s = wave; s < BGRID; s += NWAVES) {
        uint32_t c = scl[s];
        const uint32_t* rs = rb + (size_t)s * SEGCAP;
        for (uint32_t i = lane; i < c; i += 64) {
            uint32_t rec = rs[i];
            uint32_t hv = hq[rec & SRCMASK];
            atomicAdd(&acc[rec >> SRCBITS], pk2(hv));
        }
    }
    __syncthreads();
    float w0 = W2[0], w1 = W2[1], w2 = W2[2], w3 = W2[3], w4 = W2[4], w5 = W2[5];
    float b20 = b2[0], b21 = b2[1], b22 = b2[2];
    int base = b << LOCBITS;
    for (int i = threadIdx.x; i < LOCN; i += blockDim.x) {
        int n = base + i;
        if (n >= N) break;
        unsigned long long s = acc[i];
        float d = deg[n];
        float di = d > 0.0f ? 1.0f / d : 0.0f;
        float h0 = (float)(uint32_t)(s & 0xFFFFFFFFull) * INV_S_H * di;
        float h1 = (float)(uint32_t)(s >> 32) * INV_S_H * di;
        out[3 * n + 0] = h0 * w0 + h1 * w3 + b20;
        out[3 * n + 1] = h0 * w1 + h1 * w4 + b21;
        out[3 * n + 2] = h0 * w2 + h1 * w5 + b22;
    }
}

// ---------- Path B: R9-proven exact-CAP build + uint4 agg ----------
__global__ __launch_bounds__(BBLK) void k_build(const int* __restrict__ src,
                                                const int* __restrict__ dst,
                                                uint32_t* __restrict__ gcnt,
                                                uint32_t* __restrict__ recs, int E) {
    __shared__ uint32_t hist[NBUCK];
    __shared__ uint32_t cur[NBUCK];
    int blk = blockIdx.x;
    for (int i = threadIdx.x; i < NBUCK; i += blockDim.x) hist[i] = 0u;
    __syncthreads();

    int chunk = (((E + BGRID - 1) / BGRID) + 3) & ~3;
    int beg = blk * chunk;
    int end = min(E, beg + chunk);
    int cnt = end - beg;
    if (cnt < 0) cnt = 0;
    int n4 = cnt >> 2;

    const int4* d4 = reinterpret_cast<const int4*>(dst + beg);
    for (int j = threadIdx.x; j < n4; j += blockDim.x) {
        int4 d = d4[j];
        atomicAdd(&hist[((unsigned)d.x) >> LOCBITS], 1u);
        atomicAdd(&hist[((unsigned)d.y) >> LOCBITS], 1u);
        atomicAdd(&hist[((unsigned)d.z) >> LOCBITS], 1u);
        atomicAdd(&hist[((unsigned)d.w) >> LOCBITS], 1u);
    }
    for (int e = beg + (n4 << 2) + threadIdx.x; e < end; e += blockDim.x)
        atomicAdd(&hist[((unsigned)dst[e]) >> LOCBITS], 1u);
    __syncthreads();

    for (int b = threadIdx.x; b < NBUCK; b += blockDim.x)
        cur[b] = atomicAdd(&gcnt[b], hist[b]);
    __syncthreads();

    const int4* s4 = reinterpret_cast<const int4*>(src + beg);
    for (int j = threadIdx.x; j < n4; j += blockDim.x) {
        int4 d = d4[j];
        int4 s = s4[j];
        int dd[4] = {d.x, d.y, d.z, d.w};
        int ss[4] = {s.x, s.y, s.z, s.w};
#pragma unroll
        for (int q = 0; q < 4; ++q) {
            unsigned dv = (unsigned)dd[q];
            unsigned b = dv >> LOCBITS;
            unsigned loc = dv & (LOCN - 1u);
            unsigned pos = atomicAdd(&cur[b], 1u);
            recs[(size_t)b * CAP + pos] = (loc << SRCBITS) | (unsigned)ss[q];
        }
    }
    for (int e = beg + (n4 << 2) + threadIdx.x; e < end; e += blockDim.x) {
        unsigned dv = (unsigned)dst[e];
        unsigned b = dv >> LOCBITS;
        unsigned loc = dv & (LOCN - 1u);
        unsigned pos = atomicAdd(&cur[b], 1u);
        recs[(size_t)b * CAP + pos] = (loc << SRCBITS) | (unsigned)src[e];
    }
}

__global__ __launch_bounds__(AGGBLK) void k_agg1_cnt(const uint32_t* __restrict__ recs,
                                                     const uint32_t* __restrict__ gcnt,
                                                     const uint32_t* __restrict__ zq,
                                                     const float* __restrict__ b1,
                                                     float* __restrict__ deg,
                                                     uint32_t* __restrict__ hq, int N) {
    __shared__ unsigned long long acc[LOCN];
    int b = blockIdx.x;
    for (int i = threadIdx.x; i < LOCN; i += blockDim.x) acc[i] = 0ull;
    __syncthreads();
    uint32_t cnt = gcnt[b];
    const uint32_t* r = recs + (size_t)b * CAP;
    const uint4* r4 = reinterpret_cast<const uint4*>(r);
    uint32_t n4 = cnt >> 2;
    for (uint32_t j = threadIdx.x; j < n4; j += blockDim.x) {
        uint4 q = r4[j];
        uint32_t z0 = zq[q.x & SRCMASK];
        uint32_t z1v = zq[q.y & SRCMASK];
        uint32_t z2v = zq[q.z & SRCMASK];
        uint32_t z3v = zq[q.w & SRCMASK];
        atomicAdd(&acc[q.x >> SRCBITS], pk1(z0));
        atomicAdd(&acc[q.y >> SRCBITS], pk1(z1v));
        atomicAdd(&acc[q.z >> SRCBITS], pk1(z2v));
        atomicAdd(&acc[q.w >> SRCBITS], pk1(z3v));
    }
    for (uint32_t i = (n4 << 2) + threadIdx.x; i < cnt; i += blockDim.x) {
        uint32_t rec = r[i];
        atomicAdd(&acc[rec >> SRCBITS], pk1(zq[rec & SRCMASK]));
    }
    __syncthreads();
    float b10 = b1[0], b11 = b1[1];
    int base = b << LOCBITS;
    for (int i = threadIdx.x; i < LOCN; i += blockDim.x) {
        int n = base + i;
        if (n >= N) break;
        unsigned long long s = acc[i];
        float d = (float)(uint32_t)(s >> 54);
        float di = d > 0.0f ? 1.0f / d : 0.0f;
        float sqx = (float)(uint32_t)(s & 0x7FFFFFFull);
        float sqy = (float)(uint32_t)((s >> 27) & 0x7FFFFFFull);
        float mx = (sqx * INV_S_Z - B_Z * d) * di;
        float my = (sqy * INV_S_Z - B_Z * d) * di;
        float h0 = fmaxf(mx + b10, 0.0f);
        float h1 = fmaxf(my + b11, 0.0f);
        deg[n] = d;
        hq[n] = q16(h0, S_H, 0.0f) | (q16(h1, S_H, 0.0f) << 16);
    }
}

__global__ __launch_bounds__(AGGBLK) void k_agg2_cnt(const uint32_t* __restrict__ recs,
                                                     const uint32_t* __restrict__ gcnt,
                                                     const uint32_t* __restrict__ hq,
                                                     const float* __restrict__ W2,
                                                     const float* __restrict__ b2,
                                                     const float* __restrict__ deg,
                                                     float* __restrict__ out, int N) {
    __shared__ unsigned long long acc[LOCN];
    int b = blockIdx.x;
    for (int i = threadIdx.x; i < LOCN; i += blockDim.x) acc[i] = 0ull;
    __syncthreads();
    uint32_t cnt = gcnt[b];
    const uint32_t* r = recs + (size_t)b * CAP;
    const uint4* r4 = reinterpret_cast<const uint4*>(r);
    uint32_t n4 = cnt >> 2;
    for (uint32_t j = threadIdx.x; j < n4; j += blockDim.x) {
        uint4 q = r4[j];
        uint32_t h0 = hq[q.x & SRCMASK];
        uint32_t h1v = hq[q.y & SRCMASK];
        uint32_t h2v = hq[q.z & SRCMASK];
        uint32_t h3v = hq[q.w & SRCMASK];
        atomicAdd(&acc[q.x >> SRCBITS], pk2(h0));
        atomicAdd(&acc[q.y >> SRCBITS], pk2(h1v));
        atomicAdd(&acc[q.z >> SRCBITS], pk2(h2v));
        atomicAdd(&acc[q.w >> SRCBITS], pk2(h3v));
    }
    for (uint32_t i = (n4 << 2) + threadIdx.x; i < cnt; i += blockDim.x) {
        uint32_t rec = r[i];
        atomicAdd(&acc[rec >> SRCBITS], pk2(hq[rec & SRCMASK]));
    }
    __syncthreads();
    float w0 = W2[0], w1 = W2[1], w2 = W2[2], w3 = W2[3], w4 = W2[4], w5 = W2[5];
    float b20 = b2[0], b21 = b2[1], b22 = b2[2];
    int base = b << LOCBITS;
    for (int i = threadIdx.x; i < LOCN; i += blockDim.x) {
        int n = base + i;
        if (n >= N) break;
        unsigned long long s = acc[i];
        float d = deg[n];
        float di = d > 0.0f ? 1.0f / d : 0.0f;
        float h0 = (float)(uint32_t)(s & 0xFFFFFFFFull) * INV_S_H * di;
        float h1 = (float)(uint32_t)(s >> 32) * INV_S_H * di;
        out[3 * n + 0] = h0 * w0 + h1 * w3 + b20;
        out[3 * n + 1] = h0 * w1 + h1 * w4 + b21;
        out[3 * n + 2] = h0 * w2 + h1 * w5 + b22;
    }
}

// ---------- Path C: fallback (global atomics, full fp32) ----------
__global__ void k_transform1f(const float* __restrict__ feat,
                              const float* __restrict__ W1,
                              float* __restrict__ z1, int N) {
    int i = blockIdx.x * blockDim.x + threadIdx.x;
    if (i >= N) return;
    float f0 = feat[3 * i + 0];
    float f1 = feat[3 * i + 1];
    float f2 = feat[3 * i + 2];
    float2 z;
    z.x = f0 * W1[0] + f1 * W1[2] + f2 * W1[4];
    z.y = f0 * W1[1] + f1 * W1[3] + f2 * W1[5];
    reinterpret_cast<float2*>(z1)[i] = z;
}
__global__ void k_edge1(const int* __restrict__ src, const int* __restrict__ dst,
                        const float* __restrict__ z1,
                        float* __restrict__ agg1, float* __restrict__ deg, int E) {
    int t = blockIdx.x * blockDim.x + threadIdx.x;
    int stride = gridDim.x * blockDim.x;
    const float2* z = reinterpret_cast<const float2*>(z1);
    for (int e = t; e < E; e += stride) {
        int s = src[e], d = dst[e];
        float2 v = z[s];
        atomicAdd(&agg1[2 * d + 0], v.x);
        atomicAdd(&agg1[2 * d + 1], v.y);
        atomicAdd(&deg[d], 1.0f);
    }
}
__global__ void k_mid(const float* __restrict__ agg1, const float* __restrict__ deg,
                      const float* __restrict__ b1, const float* __restrict__ W2,
                      float* __restrict__ z2, int N) {
    int i = blockIdx.x * blockDim.x + threadIdx.x;
    if (i >= N) return;
    float dgv = deg[i];
    float di = dgv > 0.0f ? 1.0f / dgv : 0.0f;
    float2 a = reinterpret_cast<const float2*>(agg1)[i];
    float h0 = fmaxf(a.x * di + b1[0], 0.0f);
    float h1 = fmaxf(a.y * di + b1[1], 0.0f);
    z2[3 * i + 0] = h0 * W2[0] + h1 * W2[3];
    z2[3 * i + 1] = h0 * W2[1] + h1 * W2[4];
    z2[3 * i + 2] = h0 * W2[2] + h1 * W2[5];
}
__global__ void k_edge2(const int* __restrict__ src, const int* __restrict__ dst,
                        const float* __restrict__ z2, float* __restrict__ agg2, int E) {
    int t = blockIdx.x * blockDim.x + threadIdx.x;
    int stride = gridDim.x * blockDim.x;
    for (int e = t; e < E; e += stride) {
        int sv = src[e], dv = dst[e];
        atomicAdd(&agg2[3 * dv + 0], z2[3 * sv + 0]);
        atomicAdd(&agg2[3 * dv + 1], z2[3 * sv + 1]);
        atomicAdd(&agg2[3 * dv + 2], z2[3 * sv + 2]);
    }
}
__global__ void k_out(const float* __restrict__ agg2, const float* __restrict__ deg,
                      const float* __restrict__ b2, float* __restrict__ out, int N) {
    int i = blockIdx.x * blockDim.x + threadIdx.x;
    if (i >= N) return;
    float dgv = deg[i];
    float di = dgv > 0.0f ? 1.0f / dgv : 0.0f;
    out[3 * i + 0] = agg2[3 * i + 0] * di + b2[0];
    out[3 * i + 1] = agg2[3 * i + 1] * di + b2[1];
    out[3 * i + 2] = agg2[3 * i + 2] * di + b2[2];
}

extern "C" void kernel_launch(void* const* d_in, const int* in_sizes, int n_in,
                              void* d_out, int out_size, void* d_ws, size_t ws_size,
                              hipStream_t stream) {
    const float* feat = (const float*)d_in[0];
    const float* W1   = (const float*)d_in[1];
    const float* b1   = (const float*)d_in[2];
    const float* W2   = (const float*)d_in[3];
    const float* b2   = (const float*)d_in[4];
    const int* edge_src = (const int*)d_in[5];
    const int* edge_dst = (const int*)d_in[6];
    float* out = (float*)d_out;

    int N = in_sizes[0] / 3;
    int E = in_sizes[5];

    const int BLK = 256;
    int node_grid = (N + BLK - 1) / BLK;

    bool dims_ok = (N <= (1 << SRCBITS)) && (N <= (NBUCK << LOCBITS));
    bool deg_ok = ((double)E / (double)(N > 0 ? N : 1)) <= 256.0;

    // ---- path A sizing/gates ----
    size_t a_rec = 0;
    size_t a_cnt = a_rec + (size_t)NBUCK * BGRID * SEGCAP;
    size_t a_deg = a_cnt + (size_t)NBUCK * BGRID;
    size_t a_zq  = a_deg + (size_t)N;
    size_t a_hq  = a_zq + (size_t)N;
    size_t needA = (a_hq + (size_t)N) * 4;
    double chunk = (double)(((E + BGRID - 1) / BGRID + 3) & ~3);
    double mean_pb = chunk / (double)NBUCK;
    bool seg_ok = (mean_pb + 6.5 * __builtin_sqrt(mean_pb + 1.0) + 8.0) <= (double)SEGCAP;

    // ---- path B sizing/gates ----
    size_t b_rec = 0;
    size_t b_cnt = b_rec + (size_t)NBUCK * CAP;
    size_t b_deg = b_cnt + NBUCK;
    size_t b_zq  = b_deg + (size_t)N;
    size_t b_hq  = b_zq + (size_t)N;
    size_t needB = (b_hq + (size_t)N) * 4;
    double mean_cap = (double)E / (double)NBUCK;
    bool cap_ok = (mean_cap + 8.0 * __builtin_sqrt(mean_cap + 1.0) + 64.0) <= (double)CAP;

    if (dims_ok && deg_ok && seg_ok && ws_size >= needA) {
        uint32_t* recs = (uint32_t*)d_ws + a_rec;
        uint32_t* scnt = (uint32_t*)d_ws + a_cnt;
        float*    deg  = (float*)d_ws + a_deg;
        uint32_t* zq   = (uint32_t*)d_ws + a_zq;
        uint32_t* hq   = (uint32_t*)d_ws + a_hq;

        k_transform1<<<node_grid, BLK, 0, stream>>>(feat, W1, zq, N);
        k_build2<<<BGRID, BBLK, 0, stream>>>(edge_src, edge_dst, scnt, recs, E);
        k_agg1_seg<<<NBUCK, AGGBLK, 0, stream>>>(recs, scnt, zq, b1, deg, hq, N);
        k_agg2_seg<<<NBUCK, AGGBLK, 0, stream>>>(recs, scnt, hq, W2, b2, deg, out, N);
    } else if (dims_ok && deg_ok && cap_ok && ws_size >= needB) {
        uint32_t* recs = (uint32_t*)d_ws + b_rec;
        uint32_t* gcnt = (uint32_t*)d_ws + b_cnt;
        float*    deg  = (float*)d_ws + b_deg;
        uint32_t* zq   = (uint32_t*)d_ws + b_zq;
        uint32_t* hq   = (uint32_t*)d_ws + b_hq;

        hipMemsetAsync(gcnt, 0, NBUCK * sizeof(uint32_t), stream);
        k_transform1<<<node_grid, BLK, 0, stream>>>(feat, W1, zq, N);
        k_build<<<BGRID, BBLK, 0, stream>>>(edge_src, edge_dst, gcnt, recs, E);
        k_agg1_cnt<<<NBUCK, AGGBLK, 0, stream>>>(recs, gcnt, zq, b1, deg, hq, N);
        k_agg2_cnt<<<NBUCK, AGGBLK, 0, stream>>>(recs, gcnt, hq, W2, b2, deg, out, N);
    } else {
        float* ws   = (float*)d_ws;
        float* deg  = ws;                   // N
        float* agg1 = ws + N;               // 2N
        float* agg2 = ws + 3 * (size_t)N;   // 3N
        float* z1   = ws + 6 * (size_t)N;   // 2N
        float* z2   = ws + 8 * (size_t)N;   // 3N
        hipMemsetAsync(d_ws, 0, (size_t)6 * N * sizeof(float), stream);
        int edge_grid = 2048;
        k_transform1f<<<node_grid, BLK, 0, stream>>>(feat, W1, z1, N);
        k_edge1<<<edge_grid, BLK, 0, stream>>>(edge_src, edge_dst, z1, agg1, deg, E);
        k_mid<<<node_grid, BLK, 0, stream>>>(agg1, deg, b1, W2, z2, N);
        k_edge2<<<edge_grid, BLK, 0, stream>>>(edge_src, edge_dst, z2, agg2, E);
        k_out<<<node_grid, BLK, 0, stream>>>(agg2, deg, b2, out, N);
    }
}

// Round 11
// 344.901 us; speedup vs baseline: 1.3175x; 1.3175x over previous
//
#include <hip/hip_runtime.h>
#include <stdint.h>

// GCN: out = D^-1 A (relu(D^-1 A (feat W1) + b1) W2) + b2
//
// R9-proven pipeline (4 kernels, no sort, zero global data atomics), with
// BGRID=1024 (was 512): 4 blocks/CU for k_build -> 32 waves/CU latency hiding.
//   k_transform1 : zq = pack16x2(feat @ W1)   [N] u32  (4 MB -> L2-resident)
//   k_build      : bucket edges by dst into fixed-CAP regions (LDS hist +
//                  one global reservation atomic per (block,bucket)).
//   k_agg1       : per bucket: gather zq[src] (L2-resident), ONE u64 LDS
//                  atomic per edge (qx|qy|count).  h -> hq packed, deg.
//   k_agg2       : same over hq; epilogue out = (sum/deg/S_H) @ W2 + b2.
//
// ws words: recs[NBUCK*CAP] | gcnt[NBUCK] | deg[N] | zq[N] | hq[N]

#define BUCKBITS 9
#define NBUCK (1 << BUCKBITS)      // 512 dst buckets
#define LOCBITS 11
#define LOCN (1 << LOCBITS)        // 2048 nodes / bucket
#define SRCBITS 20
#define SRCMASK ((1u << SRCBITS) - 1u)
#define CAP 35072                  // mean 31250 + ~21 sigma (uniform dst)
#define BBLK 512
#define BGRID 1024                 // was 512: 4 blocks/CU -> 2x waves for latency hiding
#define AGGBLK 1024

#define S_Z 1024.0f
#define INV_S_Z (1.0f / 1024.0f)
#define B_Z 32.0f
#define S_H 2048.0f
#define INV_S_H (1.0f / 2048.0f)

__device__ __forceinline__ uint32_t q16(float v, float scale, float bias) {
    float f = (v + bias) * scale;
    f = fminf(fmaxf(f, 0.0f), 65535.0f);
    return (uint32_t)__builtin_rintf(f);
}

__device__ __forceinline__ unsigned long long pk1(uint32_t zv) {
    return (unsigned long long)(zv & 0xFFFFu) |
           ((unsigned long long)(zv >> 16) << 27) | (1ull << 54);
}
__device__ __forceinline__ unsigned long long pk2(uint32_t hv) {
    return (unsigned long long)(hv & 0xFFFFu) |
           ((unsigned long long)(hv >> 16) << 32);
}

__global__ void k_transform1(const float* __restrict__ feat,
                             const float* __restrict__ W1,
                             uint32_t* __restrict__ zq, int N) {
    int i = blockIdx.x * blockDim.x + threadIdx.x;
    if (i >= N) return;
    float f0 = feat[3 * i + 0];
    float f1 = feat[3 * i + 1];
    float f2 = feat[3 * i + 2];
    float zx = f0 * W1[0] + f1 * W1[2] + f2 * W1[4];
    float zy = f0 * W1[1] + f1 * W1[3] + f2 * W1[5];
    zq[i] = q16(zx, S_Z, B_Z) | (q16(zy, S_Z, B_Z) << 16);
}

// ---- R5/R9-proven build (512 threads), grid = BGRID ----
__global__ __launch_bounds__(BBLK) void k_build(const int* __restrict__ src,
                                                const int* __restrict__ dst,
                                                uint32_t* __restrict__ gcnt,
                                                uint32_t* __restrict__ recs, int E) {
    __shared__ uint32_t hist[NBUCK];
    __shared__ uint32_t cur[NBUCK];
    int blk = blockIdx.x;
    for (int i = threadIdx.x; i < NBUCK; i += blockDim.x) hist[i] = 0u;
    __syncthreads();

    int chunk = (((E + (int)gridDim.x - 1) / (int)gridDim.x) + 3) & ~3;
    int beg = blk * chunk;
    int end = min(E, beg + chunk);
    int cnt = end - beg;
    if (cnt < 0) cnt = 0;
    int n4 = cnt >> 2;

    const int4* d4 = reinterpret_cast<const int4*>(dst + beg);
    for (int j = threadIdx.x; j < n4; j += blockDim.x) {
        int4 d = d4[j];
        atomicAdd(&hist[((unsigned)d.x) >> LOCBITS], 1u);
        atomicAdd(&hist[((unsigned)d.y) >> LOCBITS], 1u);
        atomicAdd(&hist[((unsigned)d.z) >> LOCBITS], 1u);
        atomicAdd(&hist[((unsigned)d.w) >> LOCBITS], 1u);
    }
    for (int e = beg + (n4 << 2) + threadIdx.x; e < end; e += blockDim.x)
        atomicAdd(&hist[((unsigned)dst[e]) >> LOCBITS], 1u);
    __syncthreads();

    for (int b = threadIdx.x; b < NBUCK; b += blockDim.x)
        cur[b] = atomicAdd(&gcnt[b], hist[b]);
    __syncthreads();

    const int4* s4 = reinterpret_cast<const int4*>(src + beg);
    for (int j = threadIdx.x; j < n4; j += blockDim.x) {
        int4 d = d4[j];
        int4 s = s4[j];
        int dd[4] = {d.x, d.y, d.z, d.w};
        int ss[4] = {s.x, s.y, s.z, s.w};
#pragma unroll
        for (int q = 0; q < 4; ++q) {
            unsigned dv = (unsigned)dd[q];
            unsigned b = dv >> LOCBITS;
            unsigned loc = dv & (LOCN - 1u);
            unsigned pos = atomicAdd(&cur[b], 1u);
            recs[(size_t)b * CAP + pos] = (loc << SRCBITS) | (unsigned)ss[q];
        }
    }
    for (int e = beg + (n4 << 2) + threadIdx.x; e < end; e += blockDim.x) {
        unsigned dv = (unsigned)dst[e];
        unsigned b = dv >> LOCBITS;
        unsigned loc = dv & (LOCN - 1u);
        unsigned pos = atomicAdd(&cur[b], 1u);
        recs[(size_t)b * CAP + pos] = (loc << SRCBITS) | (unsigned)src[e];
    }
}

// layer-1 aggregation: 1 u32 gather + 1 u64 LDS atomic per edge (raw ints)
__global__ __launch_bounds__(AGGBLK) void k_agg1(const uint32_t* __restrict__ recs,
                                                 const uint32_t* __restrict__ gcnt,
                                                 const uint32_t* __restrict__ zq,
                                                 const float* __restrict__ b1,
                                                 float* __restrict__ deg,
                                                 uint32_t* __restrict__ hq, int N) {
    __shared__ unsigned long long acc[LOCN];   // 16 KB
    int b = blockIdx.x;
    for (int i = threadIdx.x; i < LOCN; i += blockDim.x) acc[i] = 0ull;
    __syncthreads();
    uint32_t cnt = gcnt[b];
    const uint32_t* r = recs + (size_t)b * CAP;
    const uint4* r4 = reinterpret_cast<const uint4*>(r);
    uint32_t n4 = cnt >> 2;
    for (uint32_t j = threadIdx.x; j < n4; j += blockDim.x) {
        uint4 q = r4[j];
        uint32_t z0 = zq[q.x & SRCMASK];
        uint32_t z1v = zq[q.y & SRCMASK];
        uint32_t z2v = zq[q.z & SRCMASK];
        uint32_t z3v = zq[q.w & SRCMASK];
        atomicAdd(&acc[q.x >> SRCBITS], pk1(z0));
        atomicAdd(&acc[q.y >> SRCBITS], pk1(z1v));
        atomicAdd(&acc[q.z >> SRCBITS], pk1(z2v));
        atomicAdd(&acc[q.w >> SRCBITS], pk1(z3v));
    }
    for (uint32_t i = (n4 << 2) + threadIdx.x; i < cnt; i += blockDim.x) {
        uint32_t rec = r[i];
        atomicAdd(&acc[rec >> SRCBITS], pk1(zq[rec & SRCMASK]));
    }
    __syncthreads();
    float b10 = b1[0], b11 = b1[1];
    int base = b << LOCBITS;
    for (int i = threadIdx.x; i < LOCN; i += blockDim.x) {
        int n = base + i;
        if (n >= N) break;
        unsigned long long s = acc[i];
        float d = (float)(uint32_t)(s >> 54);
        float di = d > 0.0f ? 1.0f / d : 0.0f;
        float sqx = (float)(uint32_t)(s & 0x7FFFFFFull);
        float sqy = (float)(uint32_t)((s >> 27) & 0x7FFFFFFull);
        float mx = (sqx * INV_S_Z - B_Z * d) * di;
        float my = (sqy * INV_S_Z - B_Z * d) * di;
        float h0 = fmaxf(mx + b10, 0.0f);
        float h1 = fmaxf(my + b11, 0.0f);
        deg[n] = d;
        hq[n] = q16(h0, S_H, 0.0f) | (q16(h1, S_H, 0.0f) << 16);
    }
}

// layer-2 aggregation: 1 u32 gather + 1 u64 LDS atomic per edge (raw ints)
__global__ __launch_bounds__(AGGBLK) void k_agg2(const uint32_t* __restrict__ recs,
                                                 const uint32_t* __restrict__ gcnt,
                                                 const uint32_t* __restrict__ hq,
                                                 const float* __restrict__ W2,
                                                 const float* __restrict__ b2,
                                                 const float* __restrict__ deg,
                                                 float* __restrict__ out, int N) {
    __shared__ unsigned long long acc[LOCN];   // 16 KB
    int b = blockIdx.x;
    for (int i = threadIdx.x; i < LOCN; i += blockDim.x) acc[i] = 0ull;
    __syncthreads();
    uint32_t cnt = gcnt[b];
    const uint32_t* r = recs + (size_t)b * CAP;
    const uint4* r4 = reinterpret_cast<const uint4*>(r);
    uint32_t n4 = cnt >> 2;
    for (uint32_t j = threadIdx.x; j < n4; j += blockDim.x) {
        uint4 q = r4[j];
        uint32_t h0 = hq[q.x & SRCMASK];
        uint32_t h1v = hq[q.y & SRCMASK];
        uint32_t h2v = hq[q.z & SRCMASK];
        uint32_t h3v = hq[q.w & SRCMASK];
        atomicAdd(&acc[q.x >> SRCBITS], pk2(h0));
        atomicAdd(&acc[q.y >> SRCBITS], pk2(h1v));
        atomicAdd(&acc[q.z >> SRCBITS], pk2(h2v));
        atomicAdd(&acc[q.w >> SRCBITS], pk2(h3v));
    }
    for (uint32_t i = (n4 << 2) + threadIdx.x; i < cnt; i += blockDim.x) {
        uint32_t rec = r[i];
        atomicAdd(&acc[rec >> SRCBITS], pk2(hq[rec & SRCMASK]));
    }
    __syncthreads();
    float w0 = W2[0], w1 = W2[1], w2 = W2[2], w3 = W2[3], w4 = W2[4], w5 = W2[5];
    float b20 = b2[0], b21 = b2[1], b22 = b2[2];
    int base = b << LOCBITS;
    for (int i = threadIdx.x; i < LOCN; i += blockDim.x) {
        int n = base + i;
        if (n >= N) break;
        unsigned long long s = acc[i];
        float d = deg[n];
        float di = d > 0.0f ? 1.0f / d : 0.0f;
        float h0 = (float)(uint32_t)(s & 0xFFFFFFFFull) * INV_S_H * di;
        float h1 = (float)(uint32_t)(s >> 32) * INV_S_H * di;
        out[3 * n + 0] = h0 * w0 + h1 * w3 + b20;
        out[3 * n + 1] = h0 * w1 + h1 * w4 + b21;
        out[3 * n + 2] = h0 * w2 + h1 * w5 + b22;
    }
}

// ---------- fallback path (proven, global atomics, full fp32) ----------
__global__ void k_transform1f(const float* __restrict__ feat,
                              const float* __restrict__ W1,
                              float* __restrict__ z1, int N) {
    int i = blockIdx.x * blockDim.x + threadIdx.x;
    if (i >= N) return;
    float f0 = feat[3 * i + 0];
    float f1 = feat[3 * i + 1];
    float f2 = feat[3 * i + 2];
    float2 z;
    z.x = f0 * W1[0] + f1 * W1[2] + f2 * W1[4];
    z.y = f0 * W1[1] + f1 * W1[3] + f2 * W1[5];
    reinterpret_cast<float2*>(z1)[i] = z;
}
__global__ void k_edge1(const int* __restrict__ src, const int* __restrict__ dst,
                        const float* __restrict__ z1,
                        float* __restrict__ agg1, float* __restrict__ deg, int E) {
    int t = blockIdx.x * blockDim.x + threadIdx.x;
    int stride = gridDim.x * blockDim.x;
    const float2* z = reinterpret_cast<const float2*>(z1);
    for (int e = t; e < E; e += stride) {
        int s = src[e], d = dst[e];
        float2 v = z[s];
        atomicAdd(&agg1[2 * d + 0], v.x);
        atomicAdd(&agg1[2 * d + 1], v.y);
        atomicAdd(&deg[d], 1.0f);
    }
}
__global__ void k_mid(const float* __restrict__ agg1, const float* __restrict__ deg,
                      const float* __restrict__ b1, const float* __restrict__ W2,
                      float* __restrict__ z2, int N) {
    int i = blockIdx.x * blockDim.x + threadIdx.x;
    if (i >= N) return;
    float dgv = deg[i];
    float di = dgv > 0.0f ? 1.0f / dgv : 0.0f;
    float2 a = reinterpret_cast<const float2*>(agg1)[i];
    float h0 = fmaxf(a.x * di + b1[0], 0.0f);
    float h1 = fmaxf(a.y * di + b1[1], 0.0f);
    z2[3 * i + 0] = h0 * W2[0] + h1 * W2[3];
    z2[3 * i + 1] = h0 * W2[1] + h1 * W2[4];
    z2[3 * i + 2] = h0 * W2[2] + h1 * W2[5];
}
__global__ void k_edge2(const int* __restrict__ src, const int* __restrict__ dst,
                        const float* __restrict__ z2, float* __restrict__ agg2, int E) {
    int t = blockIdx.x * blockDim.x + threadIdx.x;
    int stride = gridDim.x * blockDim.x;
    for (int e = t; e < E; e += stride) {
        int sv = src[e], dv = dst[e];
        atomicAdd(&agg2[3 * dv + 0], z2[3 * sv + 0]);
        atomicAdd(&agg2[3 * dv + 1], z2[3 * sv + 1]);
        atomicAdd(&agg2[3 * dv + 2], z2[3 * sv + 2]);
    }
}
__global__ void k_out(const float* __restrict__ agg2, const float* __restrict__ deg,
                      const float* __restrict__ b2, float* __restrict__ out, int N) {
    int i = blockIdx.x * blockDim.x + threadIdx.x;
    if (i >= N) return;
    float dgv = deg[i];
    float di = dgv > 0.0f ? 1.0f / dgv : 0.0f;
    out[3 * i + 0] = agg2[3 * i + 0] * di + b2[0];
    out[3 * i + 1] = agg2[3 * i + 1] * di + b2[1];
    out[3 * i + 2] = agg2[3 * i + 2] * di + b2[2];
}

extern "C" void kernel_launch(void* const* d_in, const int* in_sizes, int n_in,
                              void* d_out, int out_size, void* d_ws, size_t ws_size,
                              hipStream_t stream) {
    const float* feat = (const float*)d_in[0];
    const float* W1   = (const float*)d_in[1];
    const float* b1   = (const float*)d_in[2];
    const float* W2   = (const float*)d_in[3];
    const float* b2   = (const float*)d_in[4];
    const int* edge_src = (const int*)d_in[5];
    const int* edge_dst = (const int*)d_in[6];
    float* out = (float*)d_out;

    int N = in_sizes[0] / 3;
    int E = in_sizes[5];

    // layout (4B words)
    size_t w_rec = 0;
    size_t w_cnt = w_rec + (size_t)NBUCK * CAP;
    size_t w_deg = w_cnt + NBUCK;
    size_t w_zq  = w_deg + (size_t)N;
    size_t w_hq  = w_zq + (size_t)N;
    size_t need_words = w_hq + (size_t)N;

    const int BLK = 256;
    int node_grid = (N + BLK - 1) / BLK;

    double mean = (double)E / (double)NBUCK;
    bool cap_ok = (mean + 8.0 * __builtin_sqrt(mean + 1.0) + 64.0) <= (double)CAP;
    bool dims_ok = (N <= (1 << SRCBITS)) && (N <= (NBUCK << LOCBITS));
    bool deg_ok = ((double)E / (double)(N > 0 ? N : 1)) <= 256.0;  // count-field margin

    if (dims_ok && cap_ok && deg_ok && ws_size >= need_words * 4) {
        uint32_t* recs = (uint32_t*)d_ws + w_rec;
        uint32_t* gcnt = (uint32_t*)d_ws + w_cnt;
        float*    deg  = (float*)d_ws + w_deg;
        uint32_t* zq   = (uint32_t*)d_ws + w_zq;
        uint32_t* hq   = (uint32_t*)d_ws + w_hq;

        hipMemsetAsync(gcnt, 0, NBUCK * sizeof(uint32_t), stream);
        k_transform1<<<node_grid, BLK, 0, stream>>>(feat, W1, zq, N);
        k_build<<<BGRID, BBLK, 0, stream>>>(edge_src, edge_dst, gcnt, recs, E);
        k_agg1<<<NBUCK, AGGBLK, 0, stream>>>(recs, gcnt, zq, b1, deg, hq, N);
        k_agg2<<<NBUCK, AGGBLK, 0, stream>>>(recs, gcnt, hq, W2, b2, deg, out, N);
    } else {
        // fallback: global-atomic path (needs 11N words)
        float* ws   = (float*)d_ws;
        float* deg  = ws;                   // N
        float* agg1 = ws + N;               // 2N
        float* agg2 = ws + 3 * (size_t)N;   // 3N
        float* z1   = ws + 6 * (size_t)N;   // 2N
        float* z2   = ws + 8 * (size_t)N;   // 3N
        hipMemsetAsync(d_ws, 0, (size_t)6 * N * sizeof(float), stream);
        int edge_grid = 2048;
        k_transform1f<<<node_grid, BLK, 0, stream>>>(feat, W1, z1, N);
        k_edge1<<<edge_grid, BLK, 0, stream>>>(edge_src, edge_dst, z1, agg1, deg, E);
        k_mid<<<node_grid, BLK, 0, stream>>>(agg1, deg, b1, W2, z2, N);
        k_edge2<<<edge_grid, BLK, 0, stream>>>(edge_src, edge_dst, z2, agg2, E);
        k_out<<<node_grid, BLK, 0, stream>>>(agg2, deg, b2, out, N);
    }
}

// Round 14
// 248.926 us; speedup vs baseline: 1.8255x; 1.3856x over previous
//
#include <hip/hip_runtime.h>
#include <stdint.h>

// GCN: out = D^-1 A (relu(D^-1 A (feat W1) + b1) W2) + b2
//
// Path A (4 kernels, no sort, zero global data atomics):
//   k_transform1 : zq = pack16x2(feat @ W1)   [N] u32  (4 MB -> L2-resident)
//   k_build3     : per block: LDS dst-bucket histogram -> LDS scan ->
//                  one reservation atomic per (block,bucket) -> records
//                  counting-sorted INTO LDS -> wave-per-bucket coalesced
//                  flush (runs of ~30 recs).  Fixes R9 k_build's 4.9x
//                  scattered-write sector amplification (313MB -> ~95MB).
//   k_agg1       : per bucket: gather zq[src] (L2-resident), ONE u64 LDS
//                  atomic per edge (qx|qy|count).  h -> hq packed, deg.
//   k_agg2       : same over hq; epilogue out = (sum/deg/S_H) @ W2 + b2.
// Record order within a bucket varies (atomic races) but agg sums INTEGERS
// -> bit-deterministic output.
// Path B: R9-proven k_build (BGRID 512).  Path C: global-atomic fallback.
//
// ws words: recs[NBUCK*CAP] | gcnt[NBUCK] | deg[N] | zq[N] | hq[N]

#define BUCKBITS 9
#define NBUCK (1 << BUCKBITS)      // 512 dst buckets
#define LOCBITS 11
#define LOCN (1 << LOCBITS)        // 2048 nodes / bucket
#define SRCBITS 20
#define SRCMASK ((1u << SRCBITS) - 1u)
#define CAP 35072                  // mean 31250 + ~21 sigma (uniform dst)
#define BBLK 512
#define BGRID 512                  // path B build grid (R9-proven)
#define BGRID3 1024                // path A build grid
#define CHUNKMAX 15632             // LDS staging capacity (62.5 KB)
#define AGGBLK 1024

#define S_Z 1024.0f
#define INV_S_Z (1.0f / 1024.0f)
#define B_Z 32.0f
#define S_H 2048.0f
#define INV_S_H (1.0f / 2048.0f)

__device__ __forceinline__ uint32_t q16(float v, float scale, float bias) {
    float f = (v + bias) * scale;
    f = fminf(fmaxf(f, 0.0f), 65535.0f);
    return (uint32_t)__builtin_rintf(f);
}

__device__ __forceinline__ unsigned long long pk1(uint32_t zv) {
    return (unsigned long long)(zv & 0xFFFFu) |
           ((unsigned long long)(zv >> 16) << 27) | (1ull << 54);
}
__device__ __forceinline__ unsigned long long pk2(uint32_t hv) {
    return (unsigned long long)(hv & 0xFFFFu) |
           ((unsigned long long)(hv >> 16) << 32);
}

__global__ void k_transform1(const float* __restrict__ feat,
                             const float* __restrict__ W1,
                             uint32_t* __restrict__ zq, int N) {
    int i = blockIdx.x * blockDim.x + threadIdx.x;
    if (i >= N) return;
    float f0 = feat[3 * i + 0];
    float f1 = feat[3 * i + 1];
    float f2 = feat[3 * i + 2];
    float zx = f0 * W1[0] + f1 * W1[2] + f2 * W1[4];
    float zy = f0 * W1[1] + f1 * W1[3] + f2 * W1[5];
    zq[i] = q16(zx, S_Z, B_Z) | (q16(zy, S_Z, B_Z) << 16);
}

// ---------- Path A build: LDS counting-sort + coalesced flush ----------
__global__ __launch_bounds__(BBLK) void k_build3(const int* __restrict__ src,
                                                 const int* __restrict__ dst,
                                                 uint32_t* __restrict__ gcnt,
                                                 uint32_t* __restrict__ recs, int E) {
    __shared__ uint32_t hist[NBUCK];
    __shared__ uint32_t sx[NBUCK], sy[NBUCK];
    __shared__ uint32_t lofs[NBUCK], curp[NBUCK], baseg[NBUCK];
    __shared__ uint32_t stage[CHUNKMAX];
    int blk = blockIdx.x;
    for (int i = threadIdx.x; i < NBUCK; i += blockDim.x) hist[i] = 0u;
    __syncthreads();

    int chunk = (((E + (int)gridDim.x - 1) / (int)gridDim.x) + 3) & ~3;
    int beg = blk * chunk;
    int end = min(E, beg + chunk);
    int cnt = end - beg;
    if (cnt < 0) cnt = 0;
    int n4 = cnt >> 2;

    // pass 1: histogram of dst buckets
    const int4* d4 = reinterpret_cast<const int4*>(dst + beg);
    for (int j = threadIdx.x; j < n4; j += blockDim.x) {
        int4 d = d4[j];
        atomicAdd(&hist[((unsigned)d.x) >> LOCBITS], 1u);
        atomicAdd(&hist[((unsigned)d.y) >> LOCBITS], 1u);
        atomicAdd(&hist[((unsigned)d.z) >> LOCBITS], 1u);
        atomicAdd(&hist[((unsigned)d.w) >> LOCBITS], 1u);
    }
    for (int e = beg + (n4 << 2) + threadIdx.x; e < end; e += blockDim.x)
        atomicAdd(&hist[((unsigned)dst[e]) >> LOCBITS], 1u);
    __syncthreads();

    // exclusive scan of hist -> lofs (Hillis-Steele, proven in k_sort)
    for (int i = threadIdx.x; i < NBUCK; i += blockDim.x) sx[i] = hist[i];
    __syncthreads();
    uint32_t* in = sx; uint32_t* out = sy;
    for (int off = 1; off < NBUCK; off <<= 1) {
        for (int i = threadIdx.x; i < NBUCK; i += blockDim.x)
            out[i] = in[i] + (i >= off ? in[i - off] : 0u);
        __syncthreads();
        uint32_t* t = in; in = out; out = t;
    }
    // reserve global chunk + init local cursors
    for (int b = threadIdx.x; b < NBUCK; b += blockDim.x) {
        uint32_t lo = (b > 0) ? in[b - 1] : 0u;
        lofs[b] = lo;
        curp[b] = lo;
        baseg[b] = atomicAdd(&gcnt[b], hist[b]);
    }
    __syncthreads();

    // pass 2: counting-sort records into LDS staging
    const int4* s4 = reinterpret_cast<const int4*>(src + beg);
    for (int j = threadIdx.x; j < n4; j += blockDim.x) {
        int4 d = d4[j];
        int4 s = s4[j];
        int dd[4] = {d.x, d.y, d.z, d.w};
        int ss[4] = {s.x, s.y, s.z, s.w};
#pragma unroll
        for (int q = 0; q < 4; ++q) {
            unsigned dv = (unsigned)dd[q];
            unsigned b = dv >> LOCBITS;
            unsigned loc = dv & (LOCN - 1u);
            unsigned lpos = atomicAdd(&curp[b], 1u);
            stage[lpos] = (loc << SRCBITS) | (unsigned)ss[q];
        }
    }
    for (int e = beg + (n4 << 2) + threadIdx.x; e < end; e += blockDim.x) {
        unsigned dv = (unsigned)dst[e];
        unsigned b = dv >> LOCBITS;
        unsigned loc = dv & (LOCN - 1u);
        unsigned lpos = atomicAdd(&curp[b], 1u);
        stage[lpos] = (loc << SRCBITS) | (unsigned)src[e];
    }
    __syncthreads();

    // pass 3: wave-per-bucket coalesced flush
    int wave = threadIdx.x >> 6;
    int lane = threadIdx.x & 63;
    for (int b = wave; b < NBUCK; b += (BBLK >> 6)) {
        uint32_t n = hist[b];
        uint32_t lo = lofs[b];
        uint32_t gb = baseg[b];
        uint32_t* dstp = recs + (size_t)b * CAP + gb;
        for (uint32_t i = lane; i < n; i += 64)
            dstp[i] = stage[lo + i];
    }
}

// ---------- Path B build: R9-proven (scattered writes) ----------
__global__ __launch_bounds__(BBLK) void k_build(const int* __restrict__ src,
                                                const int* __restrict__ dst,
                                                uint32_t* __restrict__ gcnt,
                                                uint32_t* __restrict__ recs, int E) {
    __shared__ uint32_t hist[NBUCK];
    __shared__ uint32_t cur[NBUCK];
    int blk = blockIdx.x;
    for (int i = threadIdx.x; i < NBUCK; i += blockDim.x) hist[i] = 0u;
    __syncthreads();

    int chunk = (((E + (int)gridDim.x - 1) / (int)gridDim.x) + 3) & ~3;
    int beg = blk * chunk;
    int end = min(E, beg + chunk);
    int cnt = end - beg;
    if (cnt < 0) cnt = 0;
    int n4 = cnt >> 2;

    const int4* d4 = reinterpret_cast<const int4*>(dst + beg);
    for (int j = threadIdx.x; j < n4; j += blockDim.x) {
        int4 d = d4[j];
        atomicAdd(&hist[((unsigned)d.x) >> LOCBITS], 1u);
        atomicAdd(&hist[((unsigned)d.y) >> LOCBITS], 1u);
        atomicAdd(&hist[((unsigned)d.z) >> LOCBITS], 1u);
        atomicAdd(&hist[((unsigned)d.w) >> LOCBITS], 1u);
    }
    for (int e = beg + (n4 << 2) + threadIdx.x; e < end; e += blockDim.x)
        atomicAdd(&hist[((unsigned)dst[e]) >> LOCBITS], 1u);
    __syncthreads();

    for (int b = threadIdx.x; b < NBUCK; b += blockDim.x)
        cur[b] = atomicAdd(&gcnt[b], hist[b]);
    __syncthreads();

    const int4* s4 = reinterpret_cast<const int4*>(src + beg);
    for (int j = threadIdx.x; j < n4; j += blockDim.x) {
        int4 d = d4[j];
        int4 s = s4[j];
        int dd[4] = {d.x, d.y, d.z, d.w};
        int ss[4] = {s.x, s.y, s.z, s.w};
#pragma unroll
        for (int q = 0; q < 4; ++q) {
            unsigned dv = (unsigned)dd[q];
            unsigned b = dv >> LOCBITS;
            unsigned loc = dv & (LOCN - 1u);
            unsigned pos = atomicAdd(&cur[b], 1u);
            recs[(size_t)b * CAP + pos] = (loc << SRCBITS) | (unsigned)ss[q];
        }
    }
    for (int e = beg + (n4 << 2) + threadIdx.x; e < end; e += blockDim.x) {
        unsigned dv = (unsigned)dst[e];
        unsigned b = dv >> LOCBITS;
        unsigned loc = dv & (LOCN - 1u);
        unsigned pos = atomicAdd(&cur[b], 1u);
        recs[(size_t)b * CAP + pos] = (loc << SRCBITS) | (unsigned)src[e];
    }
}

// layer-1 aggregation: 1 u32 gather + 1 u64 LDS atomic per edge (raw ints)
__global__ __launch_bounds__(AGGBLK) void k_agg1(const uint32_t* __restrict__ recs,
                                                 const uint32_t* __restrict__ gcnt,
                                                 const uint32_t* __restrict__ zq,
                                                 const float* __restrict__ b1,
                                                 float* __restrict__ deg,
                                                 uint32_t* __restrict__ hq, int N) {
    __shared__ unsigned long long acc[LOCN];   // 16 KB
    int b = blockIdx.x;
    for (int i = threadIdx.x; i < LOCN; i += blockDim.x) acc[i] = 0ull;
    __syncthreads();
    uint32_t cnt = gcnt[b];
    const uint32_t* r = recs + (size_t)b * CAP;
    const uint4* r4 = reinterpret_cast<const uint4*>(r);
    uint32_t n4 = cnt >> 2;
    for (uint32_t j = threadIdx.x; j < n4; j += blockDim.x) {
        uint4 q = r4[j];
        uint32_t z0 = zq[q.x & SRCMASK];
        uint32_t z1v = zq[q.y & SRCMASK];
        uint32_t z2v = zq[q.z & SRCMASK];
        uint32_t z3v = zq[q.w & SRCMASK];
        atomicAdd(&acc[q.x >> SRCBITS], pk1(z0));
        atomicAdd(&acc[q.y >> SRCBITS], pk1(z1v));
        atomicAdd(&acc[q.z >> SRCBITS], pk1(z2v));
        atomicAdd(&acc[q.w >> SRCBITS], pk1(z3v));
    }
    for (uint32_t i = (n4 << 2) + threadIdx.x; i < cnt; i += blockDim.x) {
        uint32_t rec = r[i];
        atomicAdd(&acc[rec >> SRCBITS], pk1(zq[rec & SRCMASK]));
    }
    __syncthreads();
    float b10 = b1[0], b11 = b1[1];
    int base = b << LOCBITS;
    for (int i = threadIdx.x; i < LOCN; i += blockDim.x) {
        int n = base + i;
        if (n >= N) break;
        unsigned long long s = acc[i];
        float d = (float)(uint32_t)(s >> 54);
        float di = d > 0.0f ? 1.0f / d : 0.0f;
        float sqx = (float)(uint32_t)(s & 0x7FFFFFFull);
        float sqy = (float)(uint32_t)((s >> 27) & 0x7FFFFFFull);
        float mx = (sqx * INV_S_Z - B_Z * d) * di;
        float my = (sqy * INV_S_Z - B_Z * d) * di;
        float h0 = fmaxf(mx + b10, 0.0f);
        float h1 = fmaxf(my + b11, 0.0f);
        deg[n] = d;
        hq[n] = q16(h0, S_H, 0.0f) | (q16(h1, S_H, 0.0f) << 16);
    }
}

// layer-2 aggregation: 1 u32 gather + 1 u64 LDS atomic per edge (raw ints)
__global__ __launch_bounds__(AGGBLK) void k_agg2(const uint32_t* __restrict__ recs,
                                                 const uint32_t* __restrict__ gcnt,
                                                 const uint32_t* __restrict__ hq,
                                                 const float* __restrict__ W2,
                                                 const float* __restrict__ b2,
                                                 const float* __restrict__ deg,
                                                 float* __restrict__ out, int N) {
    __shared__ unsigned long long acc[LOCN];   // 16 KB
    int b = blockIdx.x;
    for (int i = threadIdx.x; i < LOCN; i += blockDim.x) acc[i] = 0ull;
    __syncthreads();
    uint32_t cnt = gcnt[b];
    const uint32_t* r = recs + (size_t)b * CAP;
    const uint4* r4 = reinterpret_cast<const uint4*>(r);
    uint32_t n4 = cnt >> 2;
    for (uint32_t j = threadIdx.x; j < n4; j += blockDim.x) {
        uint4 q = r4[j];
        uint32_t h0 = hq[q.x & SRCMASK];
        uint32_t h1v = hq[q.y & SRCMASK];
        uint32_t h2v = hq[q.z & SRCMASK];
        uint32_t h3v = hq[q.w & SRCMASK];
        atomicAdd(&acc[q.x >> SRCBITS], pk2(h0));
        atomicAdd(&acc[q.y >> SRCBITS], pk2(h1v));
        atomicAdd(&acc[q.z >> SRCBITS], pk2(h2v));
        atomicAdd(&acc[q.w >> SRCBITS], pk2(h3v));
    }
    for (uint32_t i = (n4 << 2) + threadIdx.x; i < cnt; i += blockDim.x) {
        uint32_t rec = r[i];
        atomicAdd(&acc[rec >> SRCBITS], pk2(hq[rec & SRCMASK]));
    }
    __syncthreads();
    float w0 = W2[0], w1 = W2[1], w2 = W2[2], w3 = W2[3], w4 = W2[4], w5 = W2[5];
    float b20 = b2[0], b21 = b2[1], b22 = b2[2];
    int base = b << LOCBITS;
    for (int i = threadIdx.x; i < LOCN; i += blockDim.x) {
        int n = base + i;
        if (n >= N) break;
        unsigned long long s = acc[i];
        float d = deg[n];
        float di = d > 0.0f ? 1.0f / d : 0.0f;
        float h0 = (float)(uint32_t)(s & 0xFFFFFFFFull) * INV_S_H * di;
        float h1 = (float)(uint32_t)(s >> 32) * INV_S_H * di;
        out[3 * n + 0] = h0 * w0 + h1 * w3 + b20;
        out[3 * n + 1] = h0 * w1 + h1 * w4 + b21;
        out[3 * n + 2] = h0 * w2 + h1 * w5 + b22;
    }
}

// ---------- Path C: fallback (global atomics, full fp32) ----------
__global__ void k_transform1f(const float* __restrict__ feat,
                              const float* __restrict__ W1,
                              float* __restrict__ z1, int N) {
    int i = blockIdx.x * blockDim.x + threadIdx.x;
    if (i >= N) return;
    float f0 = feat[3 * i + 0];
    float f1 = feat[3 * i + 1];
    float f2 = feat[3 * i + 2];
    float2 z;
    z.x = f0 * W1[0] + f1 * W1[2] + f2 * W1[4];
    z.y = f0 * W1[1] + f1 * W1[3] + f2 * W1[5];
    reinterpret_cast<float2*>(z1)[i] = z;
}
__global__ void k_edge1(const int* __restrict__ src, const int* __restrict__ dst,
                        const float* __restrict__ z1,
                        float* __restrict__ agg1, float* __restrict__ deg, int E) {
    int t = blockIdx.x * blockDim.x + threadIdx.x;
    int stride = gridDim.x * blockDim.x;
    const float2* z = reinterpret_cast<const float2*>(z1);
    for (int e = t; e < E; e += stride) {
        int s = src[e], d = dst[e];
        float2 v = z[s];
        atomicAdd(&agg1[2 * d + 0], v.x);
        atomicAdd(&agg1[2 * d + 1], v.y);
        atomicAdd(&deg[d], 1.0f);
    }
}
__global__ void k_mid(const float* __restrict__ agg1, const float* __restrict__ deg,
                      const float* __restrict__ b1, const float* __restrict__ W2,
                      float* __restrict__ z2, int N) {
    int i = blockIdx.x * blockDim.x + threadIdx.x;
    if (i >= N) return;
    float dgv = deg[i];
    float di = dgv > 0.0f ? 1.0f / dgv : 0.0f;
    float2 a = reinterpret_cast<const float2*>(agg1)[i];
    float h0 = fmaxf(a.x * di + b1[0], 0.0f);
    float h1 = fmaxf(a.y * di + b1[1], 0.0f);
    z2[3 * i + 0] = h0 * W2[0] + h1 * W2[3];
    z2[3 * i + 1] = h0 * W2[1] + h1 * W2[4];
    z2[3 * i + 2] = h0 * W2[2] + h1 * W2[5];
}
__global__ void k_edge2(const int* __restrict__ src, const int* __restrict__ dst,
                        const float* __restrict__ z2, float* __restrict__ agg2, int E) {
    int t = blockIdx.x * blockDim.x + threadIdx.x;
    int stride = gridDim.x * blockDim.x;
    for (int e = t; e < E; e += stride) {
        int sv = src[e], dv = dst[e];
        atomicAdd(&agg2[3 * dv + 0], z2[3 * sv + 0]);
        atomicAdd(&agg2[3 * dv + 1], z2[3 * sv + 1]);
        atomicAdd(&agg2[3 * dv + 2], z2[3 * sv + 2]);
    }
}
__global__ void k_out(const float* __restrict__ agg2, const float* __restrict__ deg,
                      const float* __restrict__ b2, float* __restrict__ out, int N) {
    int i = blockIdx.x * blockDim.x + threadIdx.x;
    if (i >= N) return;
    float dgv = deg[i];
    float di = dgv > 0.0f ? 1.0f / dgv : 0.0f;
    out[3 * i + 0] = agg2[3 * i + 0] * di + b2[0];
    out[3 * i + 1] = agg2[3 * i + 1] * di + b2[1];
    out[3 * i + 2] = agg2[3 * i + 2] * di + b2[2];
}

extern "C" void kernel_launch(void* const* d_in, const int* in_sizes, int n_in,
                              void* d_out, int out_size, void* d_ws, size_t ws_size,
                              hipStream_t stream) {
    const float* feat = (const float*)d_in[0];
    const float* W1   = (const float*)d_in[1];
    const float* b1   = (const float*)d_in[2];
    const float* W2   = (const float*)d_in[3];
    const float* b2   = (const float*)d_in[4];
    const int* edge_src = (const int*)d_in[5];
    const int* edge_dst = (const int*)d_in[6];
    float* out = (float*)d_out;

    int N = in_sizes[0] / 3;
    int E = in_sizes[5];

    // layout (4B words)
    size_t w_rec = 0;
    size_t w_cnt = w_rec + (size_t)NBUCK * CAP;
    size_t w_deg = w_cnt + NBUCK;
    size_t w_zq  = w_deg + (size_t)N;
    size_t w_hq  = w_zq + (size_t)N;
    size_t need_words = w_hq + (size_t)N;

    const int BLK = 256;
    int node_grid = (N + BLK - 1) / BLK;

    double mean = (double)E / (double)NBUCK;
    bool cap_ok = (mean + 8.0 * __builtin_sqrt(mean + 1.0) + 64.0) <= (double)CAP;
    bool dims_ok = (N <= (1 << SRCBITS)) && (N <= (NBUCK << LOCBITS));
    bool deg_ok = ((double)E / (double)(N > 0 ? N : 1)) <= 256.0;  // count-field margin
    int chunk3 = (((E + BGRID3 - 1) / BGRID3) + 3) & ~3;
    bool stage_ok = chunk3 <= CHUNKMAX;

    if (dims_ok && cap_ok && deg_ok && ws_size >= need_words * 4) {
        uint32_t* recs = (uint32_t*)d_ws + w_rec;
        uint32_t* gcnt = (uint32_t*)d_ws + w_cnt;
        float*    deg  = (float*)d_ws + w_deg;
        uint32_t* zq   = (uint32_t*)d_ws + w_zq;
        uint32_t* hq   = (uint32_t*)d_ws + w_hq;

        hipMemsetAsync(gcnt, 0, NBUCK * sizeof(uint32_t), stream);
        k_transform1<<<node_grid, BLK, 0, stream>>>(feat, W1, zq, N);
        if (stage_ok)
            k_build3<<<BGRID3, BBLK, 0, stream>>>(edge_src, edge_dst, gcnt, recs, E);
        else
            k_build<<<BGRID, BBLK, 0, stream>>>(edge_src, edge_dst, gcnt, recs, E);
        k_agg1<<<NBUCK, AGGBLK, 0, stream>>>(recs, gcnt, zq, b1, deg, hq, N);
        k_agg2<<<NBUCK, AGGBLK, 0, stream>>>(recs, gcnt, hq, W2, b2, deg, out, N);
    } else {
        // fallback: global-atomic path (needs 11N words)
        float* ws   = (float*)d_ws;
        float* deg  = ws;                   // N
        float* agg1 = ws + N;               // 2N
        float* agg2 = ws + 3 * (size_t)N;   // 3N
        float* z1   = ws + 6 * (size_t)N;   // 2N
        float* z2   = ws + 8 * (size_t)N;   // 3N
        hipMemsetAsync(d_ws, 0, (size_t)6 * N * sizeof(float), stream);
        int edge_grid = 2048;
        k_transform1f<<<node_grid, BLK, 0, stream>>>(feat, W1, z1, N);
        k_edge1<<<edge_grid, BLK, 0, stream>>>(edge_src, edge_dst, z1, agg1, deg, E);
        k_mid<<<node_grid, BLK, 0, stream>>>(agg1, deg, b1, W2, z2, N);
        k_edge2<<<edge_grid, BLK, 0, stream>>>(edge_src, edge_dst, z2, agg2, E);
        k_out<<<node_grid, BLK, 0, stream>>>(agg2, deg, b2, out, N);
    }
}

// Round 15
// 246.331 us; speedup vs baseline: 1.8447x; 1.0105x over previous
//
#include <hip/hip_runtime.h>
#include <stdint.h>

// GCN: out = D^-1 A (relu(D^-1 A (feat W1) + b1) W2) + b2
//
// Path A (4 dispatches, no sort, zero global data atomics):
//   k_transform1 : zq = pack16x2(feat @ W1) [N] u32 (4 MB -> L2-resident);
//                  block 0 also zeroes gcnt (replaces memset dispatch).
//   k_build3     : per block: LDS dst-bucket histogram -> LDS scan ->
//                  one reservation atomic per (block,bucket) -> records
//                  counting-sorted INTO LDS -> wave-per-bucket coalesced
//                  flush.  (R14-proven: 95us, write-amp 1.17x)
//   k_agg1       : per bucket: gather zq[src] (L2-resident), ONE u64 LDS
//                  atomic per edge (qx|qy|count).  h -> hq packed, deg.
//   k_agg2       : same over hq; epilogue out = (sum/deg/S_H) @ W2 + b2.
// Record order within a bucket varies (atomic races) but agg sums INTEGERS
// -> bit-deterministic output.
// Path B: R9-proven k_build (BGRID 512).  Path C: global-atomic fallback.
//
// ws words: recs[NBUCK*CAP] | gcnt[NBUCK] | deg[N] | zq[N] | hq[N]

#define BUCKBITS 9
#define NBUCK (1 << BUCKBITS)      // 512 dst buckets
#define LOCBITS 11
#define LOCN (1 << LOCBITS)        // 2048 nodes / bucket
#define SRCBITS 20
#define SRCMASK ((1u << SRCBITS) - 1u)
#define CAP 35072                  // mean 31250 + ~21 sigma (uniform dst)
#define BBLK 512
#define BGRID 512                  // path B build grid (R9-proven)
#define BGRID3 1024                // path A build grid
#define CHUNKMAX 15632             // LDS staging capacity (62.5 KB)
#define AGGBLK 1024

#define S_Z 1024.0f
#define INV_S_Z (1.0f / 1024.0f)
#define B_Z 32.0f
#define S_H 2048.0f
#define INV_S_H (1.0f / 2048.0f)

__device__ __forceinline__ uint32_t q16(float v, float scale, float bias) {
    float f = (v + bias) * scale;
    f = fminf(fmaxf(f, 0.0f), 65535.0f);
    return (uint32_t)__builtin_rintf(f);
}

__device__ __forceinline__ unsigned long long pk1(uint32_t zv) {
    return (unsigned long long)(zv & 0xFFFFu) |
           ((unsigned long long)(zv >> 16) << 27) | (1ull << 54);
}
__device__ __forceinline__ unsigned long long pk2(uint32_t hv) {
    return (unsigned long long)(hv & 0xFFFFu) |
           ((unsigned long long)(hv >> 16) << 32);
}

// transform + gcnt zeroing (block 0) -- removes the memset dispatch
__global__ void k_transform1(const float* __restrict__ feat,
                             const float* __restrict__ W1,
                             uint32_t* __restrict__ zq,
                             uint32_t* __restrict__ gcnt, int N) {
    if (blockIdx.x == 0) {
        for (int i = threadIdx.x; i < NBUCK; i += blockDim.x) gcnt[i] = 0u;
    }
    int i = blockIdx.x * blockDim.x + threadIdx.x;
    if (i >= N) return;
    float f0 = feat[3 * i + 0];
    float f1 = feat[3 * i + 1];
    float f2 = feat[3 * i + 2];
    float zx = f0 * W1[0] + f1 * W1[2] + f2 * W1[4];
    float zy = f0 * W1[1] + f1 * W1[3] + f2 * W1[5];
    zq[i] = q16(zx, S_Z, B_Z) | (q16(zy, S_Z, B_Z) << 16);
}

// ---------- Path A build: LDS counting-sort + coalesced flush (R14-proven) ----------
__global__ __launch_bounds__(BBLK) void k_build3(const int* __restrict__ src,
                                                 const int* __restrict__ dst,
                                                 uint32_t* __restrict__ gcnt,
                                                 uint32_t* __restrict__ recs, int E) {
    __shared__ uint32_t hist[NBUCK];
    __shared__ uint32_t sx[NBUCK], sy[NBUCK];
    __shared__ uint32_t lofs[NBUCK], curp[NBUCK], baseg[NBUCK];
    __shared__ uint32_t stage[CHUNKMAX];
    int blk = blockIdx.x;
    for (int i = threadIdx.x; i < NBUCK; i += blockDim.x) hist[i] = 0u;
    __syncthreads();

    int chunk = (((E + (int)gridDim.x - 1) / (int)gridDim.x) + 3) & ~3;
    int beg = blk * chunk;
    int end = min(E, beg + chunk);
    int cnt = end - beg;
    if (cnt < 0) cnt = 0;
    int n4 = cnt >> 2;

    // pass 1: histogram of dst buckets
    const int4* d4 = reinterpret_cast<const int4*>(dst + beg);
    for (int j = threadIdx.x; j < n4; j += blockDim.x) {
        int4 d = d4[j];
        atomicAdd(&hist[((unsigned)d.x) >> LOCBITS], 1u);
        atomicAdd(&hist[((unsigned)d.y) >> LOCBITS], 1u);
        atomicAdd(&hist[((unsigned)d.z) >> LOCBITS], 1u);
        atomicAdd(&hist[((unsigned)d.w) >> LOCBITS], 1u);
    }
    for (int e = beg + (n4 << 2) + threadIdx.x; e < end; e += blockDim.x)
        atomicAdd(&hist[((unsigned)dst[e]) >> LOCBITS], 1u);
    __syncthreads();

    // exclusive scan of hist -> lofs
    for (int i = threadIdx.x; i < NBUCK; i += blockDim.x) sx[i] = hist[i];
    __syncthreads();
    uint32_t* in = sx; uint32_t* out = sy;
    for (int off = 1; off < NBUCK; off <<= 1) {
        for (int i = threadIdx.x; i < NBUCK; i += blockDim.x)
            out[i] = in[i] + (i >= off ? in[i - off] : 0u);
        __syncthreads();
        uint32_t* t = in; in = out; out = t;
    }
    // reserve global chunk + init local cursors
    for (int b = threadIdx.x; b < NBUCK; b += blockDim.x) {
        uint32_t lo = (b > 0) ? in[b - 1] : 0u;
        lofs[b] = lo;
        curp[b] = lo;
        baseg[b] = atomicAdd(&gcnt[b], hist[b]);
    }
    __syncthreads();

    // pass 2: counting-sort records into LDS staging
    const int4* s4 = reinterpret_cast<const int4*>(src + beg);
    for (int j = threadIdx.x; j < n4; j += blockDim.x) {
        int4 d = d4[j];
        int4 s = s4[j];
        int dd[4] = {d.x, d.y, d.z, d.w};
        int ss[4] = {s.x, s.y, s.z, s.w};
#pragma unroll
        for (int q = 0; q < 4; ++q) {
            unsigned dv = (unsigned)dd[q];
            unsigned b = dv >> LOCBITS;
            unsigned loc = dv & (LOCN - 1u);
            unsigned lpos = atomicAdd(&curp[b], 1u);
            stage[lpos] = (loc << SRCBITS) | (unsigned)ss[q];
        }
    }
    for (int e = beg + (n4 << 2) + threadIdx.x; e < end; e += blockDim.x) {
        unsigned dv = (unsigned)dst[e];
        unsigned b = dv >> LOCBITS;
        unsigned loc = dv & (LOCN - 1u);
        unsigned lpos = atomicAdd(&curp[b], 1u);
        stage[lpos] = (loc << SRCBITS) | (unsigned)src[e];
    }
    __syncthreads();

    // pass 3: wave-per-bucket coalesced flush
    int wave = threadIdx.x >> 6;
    int lane = threadIdx.x & 63;
    for (int b = wave; b < NBUCK; b += (BBLK >> 6)) {
        uint32_t n = hist[b];
        uint32_t lo = lofs[b];
        uint32_t gb = baseg[b];
        uint32_t* dstp = recs + (size_t)b * CAP + gb;
        for (uint32_t i = lane; i < n; i += 64)
            dstp[i] = stage[lo + i];
    }
}

// ---------- Path B build: R9-proven (scattered writes) ----------
__global__ __launch_bounds__(BBLK) void k_build(const int* __restrict__ src,
                                                const int* __restrict__ dst,
                                                uint32_t* __restrict__ gcnt,
                                                uint32_t* __restrict__ recs, int E) {
    __shared__ uint32_t hist[NBUCK];
    __shared__ uint32_t cur[NBUCK];
    int blk = blockIdx.x;
    for (int i = threadIdx.x; i < NBUCK; i += blockDim.x) hist[i] = 0u;
    __syncthreads();

    int chunk = (((E + (int)gridDim.x - 1) / (int)gridDim.x) + 3) & ~3;
    int beg = blk * chunk;
    int end = min(E, beg + chunk);
    int cnt = end - beg;
    if (cnt < 0) cnt = 0;
    int n4 = cnt >> 2;

    const int4* d4 = reinterpret_cast<const int4*>(dst + beg);
    for (int j = threadIdx.x; j < n4; j += blockDim.x) {
        int4 d = d4[j];
        atomicAdd(&hist[((unsigned)d.x) >> LOCBITS], 1u);
        atomicAdd(&hist[((unsigned)d.y) >> LOCBITS], 1u);
        atomicAdd(&hist[((unsigned)d.z) >> LOCBITS], 1u);
        atomicAdd(&hist[((unsigned)d.w) >> LOCBITS], 1u);
    }
    for (int e = beg + (n4 << 2) + threadIdx.x; e < end; e += blockDim.x)
        atomicAdd(&hist[((unsigned)dst[e]) >> LOCBITS], 1u);
    __syncthreads();

    for (int b = threadIdx.x; b < NBUCK; b += blockDim.x)
        cur[b] = atomicAdd(&gcnt[b], hist[b]);
    __syncthreads();

    const int4* s4 = reinterpret_cast<const int4*>(src + beg);
    for (int j = threadIdx.x; j < n4; j += blockDim.x) {
        int4 d = d4[j];
        int4 s = s4[j];
        int dd[4] = {d.x, d.y, d.z, d.w};
        int ss[4] = {s.x, s.y, s.z, s.w};
#pragma unroll
        for (int q = 0; q < 4; ++q) {
            unsigned dv = (unsigned)dd[q];
            unsigned b = dv >> LOCBITS;
            unsigned loc = dv & (LOCN - 1u);
            unsigned pos = atomicAdd(&cur[b], 1u);
            recs[(size_t)b * CAP + pos] = (loc << SRCBITS) | (unsigned)ss[q];
        }
    }
    for (int e = beg + (n4 << 2) + threadIdx.x; e < end; e += blockDim.x) {
        unsigned dv = (unsigned)dst[e];
        unsigned b = dv >> LOCBITS;
        unsigned loc = dv & (LOCN - 1u);
        unsigned pos = atomicAdd(&cur[b], 1u);
        recs[(size_t)b * CAP + pos] = (loc << SRCBITS) | (unsigned)src[e];
    }
}

// layer-1 aggregation: 1 u32 gather + 1 u64 LDS atomic per edge (raw ints)
__global__ __launch_bounds__(AGGBLK) void k_agg1(const uint32_t* __restrict__ recs,
                                                 const uint32_t* __restrict__ gcnt,
                                                 const uint32_t* __restrict__ zq,
                                                 const float* __restrict__ b1,
                                                 float* __restrict__ deg,
                                                 uint32_t* __restrict__ hq, int N) {
    __shared__ unsigned long long acc[LOCN];   // 16 KB
    int b = blockIdx.x;
    for (int i = threadIdx.x; i < LOCN; i += blockDim.x) acc[i] = 0ull;
    __syncthreads();
    uint32_t cnt = gcnt[b];
    const uint32_t* r = recs + (size_t)b * CAP;
    const uint4* r4 = reinterpret_cast<const uint4*>(r);
    uint32_t n4 = cnt >> 2;
    for (uint32_t j = threadIdx.x; j < n4; j += blockDim.x) {
        uint4 q = r4[j];
        uint32_t z0 = zq[q.x & SRCMASK];
        uint32_t z1v = zq[q.y & SRCMASK];
        uint32_t z2v = zq[q.z & SRCMASK];
        uint32_t z3v = zq[q.w & SRCMASK];
        atomicAdd(&acc[q.x >> SRCBITS], pk1(z0));
        atomicAdd(&acc[q.y >> SRCBITS], pk1(z1v));
        atomicAdd(&acc[q.z >> SRCBITS], pk1(z2v));
        atomicAdd(&acc[q.w >> SRCBITS], pk1(z3v));
    }
    for (uint32_t i = (n4 << 2) + threadIdx.x; i < cnt; i += blockDim.x) {
        uint32_t rec = r[i];
        atomicAdd(&acc[rec >> SRCBITS], pk1(zq[rec & SRCMASK]));
    }
    __syncthreads();
    float b10 = b1[0], b11 = b1[1];
    int base = b << LOCBITS;
    for (int i = threadIdx.x; i < LOCN; i += blockDim.x) {
        int n = base + i;
        if (n >= N) break;
        unsigned long long s = acc[i];
        float d = (float)(uint32_t)(s >> 54);
        float di = d > 0.0f ? 1.0f / d : 0.0f;
        float sqx = (float)(uint32_t)(s & 0x7FFFFFFull);
        float sqy = (float)(uint32_t)((s >> 27) & 0x7FFFFFFull);
        float mx = (sqx * INV_S_Z - B_Z * d) * di;
        float my = (sqy * INV_S_Z - B_Z * d) * di;
        float h0 = fmaxf(mx + b10, 0.0f);
        float h1 = fmaxf(my + b11, 0.0f);
        deg[n] = d;
        hq[n] = q16(h0, S_H, 0.0f) | (q16(h1, S_H, 0.0f) << 16);
    }
}

// layer-2 aggregation: 1 u32 gather + 1 u64 LDS atomic per edge (raw ints)
__global__ __launch_bounds__(AGGBLK) void k_agg2(const uint32_t* __restrict__ recs,
                                                 const uint32_t* __restrict__ gcnt,
                                                 const uint32_t* __restrict__ hq,
                                                 const float* __restrict__ W2,
                                                 const float* __restrict__ b2,
                                                 const float* __restrict__ deg,
                                                 float* __restrict__ out, int N) {
    __shared__ unsigned long long acc[LOCN];   // 16 KB
    int b = blockIdx.x;
    for (int i = threadIdx.x; i < LOCN; i += blockDim.x) acc[i] = 0ull;
    __syncthreads();
    uint32_t cnt = gcnt[b];
    const uint32_t* r = recs + (size_t)b * CAP;
    const uint4* r4 = reinterpret_cast<const uint4*>(r);
    uint32_t n4 = cnt >> 2;
    for (uint32_t j = threadIdx.x; j < n4; j += blockDim.x) {
        uint4 q = r4[j];
        uint32_t h0 = hq[q.x & SRCMASK];
        uint32_t h1v = hq[q.y & SRCMASK];
        uint32_t h2v = hq[q.z & SRCMASK];
        uint32_t h3v = hq[q.w & SRCMASK];
        atomicAdd(&acc[q.x >> SRCBITS], pk2(h0));
        atomicAdd(&acc[q.y >> SRCBITS], pk2(h1v));
        atomicAdd(&acc[q.z >> SRCBITS], pk2(h2v));
        atomicAdd(&acc[q.w >> SRCBITS], pk2(h3v));
    }
    for (uint32_t i = (n4 << 2) + threadIdx.x; i < cnt; i += blockDim.x) {
        uint32_t rec = r[i];
        atomicAdd(&acc[rec >> SRCBITS], pk2(hq[rec & SRCMASK]));
    }
    __syncthreads();
    float w0 = W2[0], w1 = W2[1], w2 = W2[2], w3 = W2[3], w4 = W2[4], w5 = W2[5];
    float b20 = b2[0], b21 = b2[1], b22 = b2[2];
    int base = b << LOCBITS;
    for (int i = threadIdx.x; i < LOCN; i += blockDim.x) {
        int n = base + i;
        if (n >= N) break;
        unsigned long long s = acc[i];
        float d = deg[n];
        float di = d > 0.0f ? 1.0f / d : 0.0f;
        float h0 = (float)(uint32_t)(s & 0xFFFFFFFFull) * INV_S_H * di;
        float h1 = (float)(uint32_t)(s >> 32) * INV_S_H * di;
        out[3 * n + 0] = h0 * w0 + h1 * w3 + b20;
        out[3 * n + 1] = h0 * w1 + h1 * w4 + b21;
        out[3 * n + 2] = h0 * w2 + h1 * w5 + b22;
    }
}

// ---------- Path C: fallback (global atomics, full fp32) ----------
__global__ void k_transform1f(const float* __restrict__ feat,
                              const float* __restrict__ W1,
                              float* __restrict__ z1, int N) {
    int i = blockIdx.x * blockDim.x + threadIdx.x;
    if (i >= N) return;
    float f0 = feat[3 * i + 0];
    float f1 = feat[3 * i + 1];
    float f2 = feat[3 * i + 2];
    float2 z;
    z.x = f0 * W1[0] + f1 * W1[2] + f2 * W1[4];
    z.y = f0 * W1[1] + f1 * W1[3] + f2 * W1[5];
    reinterpret_cast<float2*>(z1)[i] = z;
}
__global__ void k_edge1(const int* __restrict__ src, const int* __restrict__ dst,
                        const float* __restrict__ z1,
                        float* __restrict__ agg1, float* __restrict__ deg, int E) {
    int t = blockIdx.x * blockDim.x + threadIdx.x;
    int stride = gridDim.x * blockDim.x;
    const float2* z = reinterpret_cast<const float2*>(z1);
    for (int e = t; e < E; e += stride) {
        int s = src[e], d = dst[e];
        float2 v = z[s];
        atomicAdd(&agg1[2 * d + 0], v.x);
        atomicAdd(&agg1[2 * d + 1], v.y);
        atomicAdd(&deg[d], 1.0f);
    }
}
__global__ void k_mid(const float* __restrict__ agg1, const float* __restrict__ deg,
                      const float* __restrict__ b1, const float* __restrict__ W2,
                      float* __restrict__ z2, int N) {
    int i = blockIdx.x * blockDim.x + threadIdx.x;
    if (i >= N) return;
    float dgv = deg[i];
    float di = dgv > 0.0f ? 1.0f / dgv : 0.0f;
    float2 a = reinterpret_cast<const float2*>(agg1)[i];
    float h0 = fmaxf(a.x * di + b1[0], 0.0f);
    float h1 = fmaxf(a.y * di + b1[1], 0.0f);
    z2[3 * i + 0] = h0 * W2[0] + h1 * W2[3];
    z2[3 * i + 1] = h0 * W2[1] + h1 * W2[4];
    z2[3 * i + 2] = h0 * W2[2] + h1 * W2[5];
}
__global__ void k_edge2(const int* __restrict__ src, const int* __restrict__ dst,
                        const float* __restrict__ z2, float* __restrict__ agg2, int E) {
    int t = blockIdx.x * blockDim.x + threadIdx.x;
    int stride = gridDim.x * blockDim.x;
    for (int e = t; e < E; e += stride) {
        int sv = src[e], dv = dst[e];
        atomicAdd(&agg2[3 * dv + 0], z2[3 * sv + 0]);
        atomicAdd(&agg2[3 * dv + 1], z2[3 * sv + 1]);
        atomicAdd(&agg2[3 * dv + 2], z2[3 * sv + 2]);
    }
}
__global__ void k_out(const float* __restrict__ agg2, const float* __restrict__ deg,
                      const float* __restrict__ b2, float* __restrict__ out, int N) {
    int i = blockIdx.x * blockDim.x + threadIdx.x;
    if (i >= N) return;
    float dgv = deg[i];
    float di = dgv > 0.0f ? 1.0f / dgv : 0.0f;
    out[3 * i + 0] = agg2[3 * i + 0] * di + b2[0];
    out[3 * i + 1] = agg2[3 * i + 1] * di + b2[1];
    out[3 * i + 2] = agg2[3 * i + 2] * di + b2[2];
}

extern "C" void kernel_launch(void* const* d_in, const int* in_sizes, int n_in,
                              void* d_out, int out_size, void* d_ws, size_t ws_size,
                              hipStream_t stream) {
    const float* feat = (const float*)d_in[0];
    const float* W1   = (const float*)d_in[1];
    const float* b1   = (const float*)d_in[2];
    const float* W2   = (const float*)d_in[3];
    const float* b2   = (const float*)d_in[4];
    const int* edge_src = (const int*)d_in[5];
    const int* edge_dst = (const int*)d_in[6];
    float* out = (float*)d_out;

    int N = in_sizes[0] / 3;
    int E = in_sizes[5];

    // layout (4B words)
    size_t w_rec = 0;
    size_t w_cnt = w_rec + (size_t)NBUCK * CAP;
    size_t w_deg = w_cnt + NBUCK;
    size_t w_zq  = w_deg + (size_t)N;
    size_t w_hq  = w_zq + (size_t)N;
    size_t need_words = w_hq + (size_t)N;

    const int BLK = 256;
    int node_grid = (N + BLK - 1) / BLK;

    double mean = (double)E / (double)NBUCK;
    bool cap_ok = (mean + 8.0 * __builtin_sqrt(mean + 1.0) + 64.0) <= (double)CAP;
    bool dims_ok = (N <= (1 << SRCBITS)) && (N <= (NBUCK << LOCBITS));
    bool deg_ok = ((double)E / (double)(N > 0 ? N : 1)) <= 256.0;  // count-field margin
    int chunk3 = (((E + BGRID3 - 1) / BGRID3) + 3) & ~3;
    bool stage_ok = chunk3 <= CHUNKMAX;

    if (dims_ok && cap_ok && deg_ok && ws_size >= need_words * 4) {
        uint32_t* recs = (uint32_t*)d_ws + w_rec;
        uint32_t* gcnt = (uint32_t*)d_ws + w_cnt;
        float*    deg  = (float*)d_ws + w_deg;
        uint32_t* zq   = (uint32_t*)d_ws + w_zq;
        uint32_t* hq   = (uint32_t*)d_ws + w_hq;

        k_transform1<<<node_grid, BLK, 0, stream>>>(feat, W1, zq, gcnt, N);
        if (stage_ok)
            k_build3<<<BGRID3, BBLK, 0, stream>>>(edge_src, edge_dst, gcnt, recs, E);
        else
            k_build<<<BGRID, BBLK, 0, stream>>>(edge_src, edge_dst, gcnt, recs, E);
        k_agg1<<<NBUCK, AGGBLK, 0, stream>>>(recs, gcnt, zq, b1, deg, hq, N);
        k_agg2<<<NBUCK, AGGBLK, 0, stream>>>(recs, gcnt, hq, W2, b2, deg, out, N);
    } else {
        // fallback: global-atomic path (needs 11N words)
        float* ws   = (float*)d_ws;
        float* deg  = ws;                   // N
        float* agg1 = ws + N;               // 2N
        float* agg2 = ws + 3 * (size_t)N;   // 3N
        float* z1   = ws + 6 * (size_t)N;   // 2N
        float* z2   = ws + 8 * (size_t)N;   // 3N
        hipMemsetAsync(d_ws, 0, (size_t)6 * N * sizeof(float), stream);
        int edge_grid = 2048;
        k_transform1f<<<node_grid, BLK, 0, stream>>>(feat, W1, z1, N);
        k_edge1<<<edge_grid, BLK, 0, stream>>>(edge_src, edge_dst, z1, agg1, deg, E);
        k_mid<<<node_grid, BLK, 0, stream>>>(agg1, deg, b1, W2, z2, N);
        k_edge2<<<edge_grid, BLK, 0, stream>>>(edge_src, edge_dst, z2, agg2, E);
        k_out<<<node_grid, BLK, 0, stream>>>(agg2, deg, b2, out, N);
    }
}

// Round 16
// 237.589 us; speedup vs baseline: 1.9126x; 1.0368x over previous
//
#include <hip/hip_runtime.h>
#include <stdint.h>

// GCN: out = D^-1 A (relu(D^-1 A (feat W1) + b1) W2) + b2
//
// Path A (4 dispatches, no sort kernel, zero global data atomics):
//   k_transform1 : zq = pack16x2(feat @ W1) [N] u32 (4 MB -> L2-resident);
//                  block 0 also zeroes gcnt (replaces memset dispatch).
//   k_build3     : per block: LDS dst-bucket histogram -> LDS scan ->
//                  one reservation atomic per (block,bucket) -> records
//                  counting-sorted INTO LDS -> wave-per-bucket coalesced
//                  flush.  R16: BBLK3=1024 (was 512) -> 32 waves/CU;
//                  chunk unchanged so flush-run length (write-amp) unchanged.
//   k_agg1       : per bucket: gather zq[src] (L2-resident), ONE u64 LDS
//                  atomic per edge (qx|qy|count).  h -> hq packed, deg.
//   k_agg2       : same over hq; epilogue out = (sum/deg/S_H) @ W2 + b2.
// Record order within a bucket varies (atomic races) but agg sums INTEGERS
// -> bit-deterministic output.
// Path B: R9-proven k_build (BGRID 512).  Path C: global-atomic fallback.
//
// ws words: recs[NBUCK*CAP] | gcnt[NBUCK] | deg[N] | zq[N] | hq[N]

#define BUCKBITS 9
#define NBUCK (1 << BUCKBITS)      // 512 dst buckets
#define LOCBITS 11
#define LOCN (1 << LOCBITS)        // 2048 nodes / bucket
#define SRCBITS 20
#define SRCMASK ((1u << SRCBITS) - 1u)
#define CAP 35072                  // mean 31250 + ~21 sigma (uniform dst)
#define BBLK 512                   // path B build block
#define BBLK3 1024                 // path A build block (R16: was 512)
#define BGRID 512                  // path B build grid (R9-proven)
#define BGRID3 1024                // path A build grid
#define CHUNKMAX 15632             // LDS staging capacity (62.5 KB)
#define AGGBLK 1024

#define S_Z 1024.0f
#define INV_S_Z (1.0f / 1024.0f)
#define B_Z 32.0f
#define S_H 2048.0f
#define INV_S_H (1.0f / 2048.0f)

__device__ __forceinline__ uint32_t q16(float v, float scale, float bias) {
    float f = (v + bias) * scale;
    f = fminf(fmaxf(f, 0.0f), 65535.0f);
    return (uint32_t)__builtin_rintf(f);
}

__device__ __forceinline__ unsigned long long pk1(uint32_t zv) {
    return (unsigned long long)(zv & 0xFFFFu) |
           ((unsigned long long)(zv >> 16) << 27) | (1ull << 54);
}
__device__ __forceinline__ unsigned long long pk2(uint32_t hv) {
    return (unsigned long long)(hv & 0xFFFFu) |
           ((unsigned long long)(hv >> 16) << 32);
}

// transform + gcnt zeroing (block 0) -- removes the memset dispatch
__global__ void k_transform1(const float* __restrict__ feat,
                             const float* __restrict__ W1,
                             uint32_t* __restrict__ zq,
                             uint32_t* __restrict__ gcnt, int N) {
    if (blockIdx.x == 0) {
        for (int i = threadIdx.x; i < NBUCK; i += blockDim.x) gcnt[i] = 0u;
    }
    int i = blockIdx.x * blockDim.x + threadIdx.x;
    if (i >= N) return;
    float f0 = feat[3 * i + 0];
    float f1 = feat[3 * i + 1];
    float f2 = feat[3 * i + 2];
    float zx = f0 * W1[0] + f1 * W1[2] + f2 * W1[4];
    float zy = f0 * W1[1] + f1 * W1[3] + f2 * W1[5];
    zq[i] = q16(zx, S_Z, B_Z) | (q16(zy, S_Z, B_Z) << 16);
}

// ---------- Path A build: LDS counting-sort + coalesced flush ----------
__global__ __launch_bounds__(BBLK3) void k_build3(const int* __restrict__ src,
                                                  const int* __restrict__ dst,
                                                  uint32_t* __restrict__ gcnt,
                                                  uint32_t* __restrict__ recs, int E) {
    __shared__ uint32_t hist[NBUCK];
    __shared__ uint32_t sx[NBUCK], sy[NBUCK];
    __shared__ uint32_t lofs[NBUCK], curp[NBUCK], baseg[NBUCK];
    __shared__ uint32_t stage[CHUNKMAX];
    int blk = blockIdx.x;
    for (int i = threadIdx.x; i < NBUCK; i += blockDim.x) hist[i] = 0u;
    __syncthreads();

    int chunk = (((E + (int)gridDim.x - 1) / (int)gridDim.x) + 3) & ~3;
    int beg = blk * chunk;
    int end = min(E, beg + chunk);
    int cnt = end - beg;
    if (cnt < 0) cnt = 0;
    int n4 = cnt >> 2;

    // pass 1: histogram of dst buckets
    const int4* d4 = reinterpret_cast<const int4*>(dst + beg);
    for (int j = threadIdx.x; j < n4; j += blockDim.x) {
        int4 d = d4[j];
        atomicAdd(&hist[((unsigned)d.x) >> LOCBITS], 1u);
        atomicAdd(&hist[((unsigned)d.y) >> LOCBITS], 1u);
        atomicAdd(&hist[((unsigned)d.z) >> LOCBITS], 1u);
        atomicAdd(&hist[((unsigned)d.w) >> LOCBITS], 1u);
    }
    for (int e = beg + (n4 << 2) + threadIdx.x; e < end; e += blockDim.x)
        atomicAdd(&hist[((unsigned)dst[e]) >> LOCBITS], 1u);
    __syncthreads();

    // exclusive scan of hist -> lofs
    for (int i = threadIdx.x; i < NBUCK; i += blockDim.x) sx[i] = hist[i];
    __syncthreads();
    uint32_t* in = sx; uint32_t* out = sy;
    for (int off = 1; off < NBUCK; off <<= 1) {
        for (int i = threadIdx.x; i < NBUCK; i += blockDim.x)
            out[i] = in[i] + (i >= off ? in[i - off] : 0u);
        __syncthreads();
        uint32_t* t = in; in = out; out = t;
    }
    // reserve global chunk + init local cursors
    for (int b = threadIdx.x; b < NBUCK; b += blockDim.x) {
        uint32_t lo = (b > 0) ? in[b - 1] : 0u;
        lofs[b] = lo;
        curp[b] = lo;
        baseg[b] = atomicAdd(&gcnt[b], hist[b]);
    }
    __syncthreads();

    // pass 2: counting-sort records into LDS staging
    const int4* s4 = reinterpret_cast<const int4*>(src + beg);
    for (int j = threadIdx.x; j < n4; j += blockDim.x) {
        int4 d = d4[j];
        int4 s = s4[j];
        int dd[4] = {d.x, d.y, d.z, d.w};
        int ss[4] = {s.x, s.y, s.z, s.w};
#pragma unroll
        for (int q = 0; q < 4; ++q) {
            unsigned dv = (unsigned)dd[q];
            unsigned b = dv >> LOCBITS;
            unsigned loc = dv & (LOCN - 1u);
            unsigned lpos = atomicAdd(&curp[b], 1u);
            stage[lpos] = (loc << SRCBITS) | (unsigned)ss[q];
        }
    }
    for (int e = beg + (n4 << 2) + threadIdx.x; e < end; e += blockDim.x) {
        unsigned dv = (unsigned)dst[e];
        unsigned b = dv >> LOCBITS;
        unsigned loc = dv & (LOCN - 1u);
        unsigned lpos = atomicAdd(&curp[b], 1u);
        stage[lpos] = (loc << SRCBITS) | (unsigned)src[e];
    }
    __syncthreads();

    // pass 3: wave-per-bucket coalesced flush
    int wave = threadIdx.x >> 6;
    int lane = threadIdx.x & 63;
    int nw = blockDim.x >> 6;
    for (int b = wave; b < NBUCK; b += nw) {
        uint32_t n = hist[b];
        uint32_t lo = lofs[b];
        uint32_t gb = baseg[b];
        uint32_t* dstp = recs + (size_t)b * CAP + gb;
        for (uint32_t i = lane; i < n; i += 64)
            dstp[i] = stage[lo + i];
    }
}

// ---------- Path B build: R9-proven (scattered writes) ----------
__global__ __launch_bounds__(BBLK) void k_build(const int* __restrict__ src,
                                                const int* __restrict__ dst,
                                                uint32_t* __restrict__ gcnt,
                                                uint32_t* __restrict__ recs, int E) {
    __shared__ uint32_t hist[NBUCK];
    __shared__ uint32_t cur[NBUCK];
    int blk = blockIdx.x;
    for (int i = threadIdx.x; i < NBUCK; i += blockDim.x) hist[i] = 0u;
    __syncthreads();

    int chunk = (((E + (int)gridDim.x - 1) / (int)gridDim.x) + 3) & ~3;
    int beg = blk * chunk;
    int end = min(E, beg + chunk);
    int cnt = end - beg;
    if (cnt < 0) cnt = 0;
    int n4 = cnt >> 2;

    const int4* d4 = reinterpret_cast<const int4*>(dst + beg);
    for (int j = threadIdx.x; j < n4; j += blockDim.x) {
        int4 d = d4[j];
        atomicAdd(&hist[((unsigned)d.x) >> LOCBITS], 1u);
        atomicAdd(&hist[((unsigned)d.y) >> LOCBITS], 1u);
        atomicAdd(&hist[((unsigned)d.z) >> LOCBITS], 1u);
        atomicAdd(&hist[((unsigned)d.w) >> LOCBITS], 1u);
    }
    for (int e = beg + (n4 << 2) + threadIdx.x; e < end; e += blockDim.x)
        atomicAdd(&hist[((unsigned)dst[e]) >> LOCBITS], 1u);
    __syncthreads();

    for (int b = threadIdx.x; b < NBUCK; b += blockDim.x)
        cur[b] = atomicAdd(&gcnt[b], hist[b]);
    __syncthreads();

    const int4* s4 = reinterpret_cast<const int4*>(src + beg);
    for (int j = threadIdx.x; j < n4; j += blockDim.x) {
        int4 d = d4[j];
        int4 s = s4[j];
        int dd[4] = {d.x, d.y, d.z, d.w};
        int ss[4] = {s.x, s.y, s.z, s.w};
#pragma unroll
        for (int q = 0; q < 4; ++q) {
            unsigned dv = (unsigned)dd[q];
            unsigned b = dv >> LOCBITS;
            unsigned loc = dv & (LOCN - 1u);
            unsigned pos = atomicAdd(&cur[b], 1u);
            recs[(size_t)b * CAP + pos] = (loc << SRCBITS) | (unsigned)ss[q];
        }
    }
    for (int e = beg + (n4 << 2) + threadIdx.x; e < end; e += blockDim.x) {
        unsigned dv = (unsigned)dst[e];
        unsigned b = dv >> LOCBITS;
        unsigned loc = dv & (LOCN - 1u);
        unsigned pos = atomicAdd(&cur[b], 1u);
        recs[(size_t)b * CAP + pos] = (loc << SRCBITS) | (unsigned)src[e];
    }
}

// layer-1 aggregation: 1 u32 gather + 1 u64 LDS atomic per edge (raw ints)
__global__ __launch_bounds__(AGGBLK) void k_agg1(const uint32_t* __restrict__ recs,
                                                 const uint32_t* __restrict__ gcnt,
                                                 const uint32_t* __restrict__ zq,
                                                 const float* __restrict__ b1,
                                                 float* __restrict__ deg,
                                                 uint32_t* __restrict__ hq, int N) {
    __shared__ unsigned long long acc[LOCN];   // 16 KB
    int b = blockIdx.x;
    for (int i = threadIdx.x; i < LOCN; i += blockDim.x) acc[i] = 0ull;
    __syncthreads();
    uint32_t cnt = gcnt[b];
    const uint32_t* r = recs + (size_t)b * CAP;
    const uint4* r4 = reinterpret_cast<const uint4*>(r);
    uint32_t n4 = cnt >> 2;
    for (uint32_t j = threadIdx.x; j < n4; j += blockDim.x) {
        uint4 q = r4[j];
        uint32_t z0 = zq[q.x & SRCMASK];
        uint32_t z1v = zq[q.y & SRCMASK];
        uint32_t z2v = zq[q.z & SRCMASK];
        uint32_t z3v = zq[q.w & SRCMASK];
        atomicAdd(&acc[q.x >> SRCBITS], pk1(z0));
        atomicAdd(&acc[q.y >> SRCBITS], pk1(z1v));
        atomicAdd(&acc[q.z >> SRCBITS], pk1(z2v));
        atomicAdd(&acc[q.w >> SRCBITS], pk1(z3v));
    }
    for (uint32_t i = (n4 << 2) + threadIdx.x; i < cnt; i += blockDim.x) {
        uint32_t rec = r[i];
        atomicAdd(&acc[rec >> SRCBITS], pk1(zq[rec & SRCMASK]));
    }
    __syncthreads();
    float b10 = b1[0], b11 = b1[1];
    int base = b << LOCBITS;
    for (int i = threadIdx.x; i < LOCN; i += blockDim.x) {
        int n = base + i;
        if (n >= N) break;
        unsigned long long s = acc[i];
        float d = (float)(uint32_t)(s >> 54);
        float di = d > 0.0f ? 1.0f / d : 0.0f;
        float sqx = (float)(uint32_t)(s & 0x7FFFFFFull);
        float sqy = (float)(uint32_t)((s >> 27) & 0x7FFFFFFull);
        float mx = (sqx * INV_S_Z - B_Z * d) * di;
        float my = (sqy * INV_S_Z - B_Z * d) * di;
        float h0 = fmaxf(mx + b10, 0.0f);
        float h1 = fmaxf(my + b11, 0.0f);
        deg[n] = d;
        hq[n] = q16(h0, S_H, 0.0f) | (q16(h1, S_H, 0.0f) << 16);
    }
}

// layer-2 aggregation: 1 u32 gather + 1 u64 LDS atomic per edge (raw ints)
__global__ __launch_bounds__(AGGBLK) void k_agg2(const uint32_t* __restrict__ recs,
                                                 const uint32_t* __restrict__ gcnt,
                                                 const uint32_t* __restrict__ hq,
                                                 const float* __restrict__ W2,
                                                 const float* __restrict__ b2,
                                                 const float* __restrict__ deg,
                                                 float* __restrict__ out, int N) {
    __shared__ unsigned long long acc[LOCN];   // 16 KB
    int b = blockIdx.x;
    for (int i = threadIdx.x; i < LOCN; i += blockDim.x) acc[i] = 0ull;
    __syncthreads();
    uint32_t cnt = gcnt[b];
    const uint32_t* r = recs + (size_t)b * CAP;
    const uint4* r4 = reinterpret_cast<const uint4*>(r);
    uint32_t n4 = cnt >> 2;
    for (uint32_t j = threadIdx.x; j < n4; j += blockDim.x) {
        uint4 q = r4[j];
        uint32_t h0 = hq[q.x & SRCMASK];
        uint32_t h1v = hq[q.y & SRCMASK];
        uint32_t h2v = hq[q.z & SRCMASK];
        uint32_t h3v = hq[q.w & SRCMASK];
        atomicAdd(&acc[q.x >> SRCBITS], pk2(h0));
        atomicAdd(&acc[q.y >> SRCBITS], pk2(h1v));
        atomicAdd(&acc[q.z >> SRCBITS], pk2(h2v));
        atomicAdd(&acc[q.w >> SRCBITS], pk2(h3v));
    }
    for (uint32_t i = (n4 << 2) + threadIdx.x; i < cnt; i += blockDim.x) {
        uint32_t rec = r[i];
        atomicAdd(&acc[rec >> SRCBITS], pk2(hq[rec & SRCMASK]));
    }
    __syncthreads();
    float w0 = W2[0], w1 = W2[1], w2 = W2[2], w3 = W2[3], w4 = W2[4], w5 = W2[5];
    float b20 = b2[0], b21 = b2[1], b22 = b2[2];
    int base = b << LOCBITS;
    for (int i = threadIdx.x; i < LOCN; i += blockDim.x) {
        int n = base + i;
        if (n >= N) break;
        unsigned long long s = acc[i];
        float d = deg[n];
        float di = d > 0.0f ? 1.0f / d : 0.0f;
        float h0 = (float)(uint32_t)(s & 0xFFFFFFFFull) * INV_S_H * di;
        float h1 = (float)(uint32_t)(s >> 32) * INV_S_H * di;
        out[3 * n + 0] = h0 * w0 + h1 * w3 + b20;
        out[3 * n + 1] = h0 * w1 + h1 * w4 + b21;
        out[3 * n + 2] = h0 * w2 + h1 * w5 + b22;
    }
}

// ---------- Path C: fallback (global atomics, full fp32) ----------
__global__ void k_transform1f(const float* __restrict__ feat,
                              const float* __restrict__ W1,
                              float* __restrict__ z1, int N) {
    int i = blockIdx.x * blockDim.x + threadIdx.x;
    if (i >= N) return;
    float f0 = feat[3 * i + 0];
    float f1 = feat[3 * i + 1];
    float f2 = feat[3 * i + 2];
    float2 z;
    z.x = f0 * W1[0] + f1 * W1[2] + f2 * W1[4];
    z.y = f0 * W1[1] + f1 * W1[3] + f2 * W1[5];
    reinterpret_cast<float2*>(z1)[i] = z;
}
__global__ void k_edge1(const int* __restrict__ src, const int* __restrict__ dst,
                        const float* __restrict__ z1,
                        float* __restrict__ agg1, float* __restrict__ deg, int E) {
    int t = blockIdx.x * blockDim.x + threadIdx.x;
    int stride = gridDim.x * blockDim.x;
    const float2* z = reinterpret_cast<const float2*>(z1);
    for (int e = t; e < E; e += stride) {
        int s = src[e], d = dst[e];
        float2 v = z[s];
        atomicAdd(&agg1[2 * d + 0], v.x);
        atomicAdd(&agg1[2 * d + 1], v.y);
        atomicAdd(&deg[d], 1.0f);
    }
}
__global__ void k_mid(const float* __restrict__ agg1, const float* __restrict__ deg,
                      const float* __restrict__ b1, const float* __restrict__ W2,
                      float* __restrict__ z2, int N) {
    int i = blockIdx.x * blockDim.x + threadIdx.x;
    if (i >= N) return;
    float dgv = deg[i];
    float di = dgv > 0.0f ? 1.0f / dgv : 0.0f;
    float2 a = reinterpret_cast<const float2*>(agg1)[i];
    float h0 = fmaxf(a.x * di + b1[0], 0.0f);
    float h1 = fmaxf(a.y * di + b1[1], 0.0f);
    z2[3 * i + 0] = h0 * W2[0] + h1 * W2[3];
    z2[3 * i + 1] = h0 * W2[1] + h1 * W2[4];
    z2[3 * i + 2] = h0 * W2[2] + h1 * W2[5];
}
__global__ void k_edge2(const int* __restrict__ src, const int* __restrict__ dst,
                        const float* __restrict__ z2, float* __restrict__ agg2, int E) {
    int t = blockIdx.x * blockDim.x + threadIdx.x;
    int stride = gridDim.x * blockDim.x;
    for (int e = t; e < E; e += stride) {
        int sv = src[e], dv = dst[e];
        atomicAdd(&agg2[3 * dv + 0], z2[3 * sv + 0]);
        atomicAdd(&agg2[3 * dv + 1], z2[3 * sv + 1]);
        atomicAdd(&agg2[3 * dv + 2], z2[3 * sv + 2]);
    }
}
__global__ void k_out(const float* __restrict__ agg2, const float* __restrict__ deg,
                      const float* __restrict__ b2, float* __restrict__ out, int N) {
    int i = blockIdx.x * blockDim.x + threadIdx.x;
    if (i >= N) return;
    float dgv = deg[i];
    float di = dgv > 0.0f ? 1.0f / dgv : 0.0f;
    out[3 * i + 0] = agg2[3 * i + 0] * di + b2[0];
    out[3 * i + 1] = agg2[3 * i + 1] * di + b2[1];
    out[3 * i + 2] = agg2[3 * i + 2] * di + b2[2];
}

extern "C" void kernel_launch(void* const* d_in, const int* in_sizes, int n_in,
                              void* d_out, int out_size, void* d_ws, size_t ws_size,
                              hipStream_t stream) {
    const float* feat = (const float*)d_in[0];
    const float* W1   = (const float*)d_in[1];
    const float* b1   = (const float*)d_in[2];
    const float* W2   = (const float*)d_in[3];
    const float* b2   = (const float*)d_in[4];
    const int* edge_src = (const int*)d_in[5];
    const int* edge_dst = (const int*)d_in[6];
    float* out = (float*)d_out;

    int N = in_sizes[0] / 3;
    int E = in_sizes[5];

    // layout (4B words)
    size_t w_rec = 0;
    size_t w_cnt = w_rec + (size_t)NBUCK * CAP;
    size_t w_deg = w_cnt + NBUCK;
    size_t w_zq  = w_deg + (size_t)N;
    size_t w_hq  = w_zq + (size_t)N;
    size_t need_words = w_hq + (size_t)N;

    const int BLK = 256;
    int node_grid = (N + BLK - 1) / BLK;

    double mean = (double)E / (double)NBUCK;
    bool cap_ok = (mean + 8.0 * __builtin_sqrt(mean + 1.0) + 64.0) <= (double)CAP;
    bool dims_ok = (N <= (1 << SRCBITS)) && (N <= (NBUCK << LOCBITS));
    bool deg_ok = ((double)E / (double)(N > 0 ? N : 1)) <= 256.0;  // count-field margin
    int chunk3 = (((E + BGRID3 - 1) / BGRID3) + 3) & ~3;
    bool stage_ok = chunk3 <= CHUNKMAX;

    if (dims_ok && cap_ok && deg_ok && ws_size >= need_words * 4) {
        uint32_t* recs = (uint32_t*)d_ws + w_rec;
        uint32_t* gcnt = (uint32_t*)d_ws + w_cnt;
        float*    deg  = (float*)d_ws + w_deg;
        uint32_t* zq   = (uint32_t*)d_ws + w_zq;
        uint32_t* hq   = (uint32_t*)d_ws + w_hq;

        k_transform1<<<node_grid, BLK, 0, stream>>>(feat, W1, zq, gcnt, N);
        if (stage_ok)
            k_build3<<<BGRID3, BBLK3, 0, stream>>>(edge_src, edge_dst, gcnt, recs, E);
        else
            k_build<<<BGRID, BBLK, 0, stream>>>(edge_src, edge_dst, gcnt, recs, E);
        k_agg1<<<NBUCK, AGGBLK, 0, stream>>>(recs, gcnt, zq, b1, deg, hq, N);
        k_agg2<<<NBUCK, AGGBLK, 0, stream>>>(recs, gcnt, hq, W2, b2, deg, out, N);
    } else {
        // fallback: global-atomic path (needs 11N words)
        float* ws   = (float*)d_ws;
        float* deg  = ws;                   // N
        float* agg1 = ws + N;               // 2N
        float* agg2 = ws + 3 * (size_t)N;   // 3N
        float* z1   = ws + 6 * (size_t)N;   // 2N
        float* z2   = ws + 8 * (size_t)N;   // 3N
        hipMemsetAsync(d_ws, 0, (size_t)6 * N * sizeof(float), stream);
        int edge_grid = 2048;
        k_transform1f<<<node_grid, BLK, 0, stream>>>(feat, W1, z1, N);
        k_edge1<<<edge_grid, BLK, 0, stream>>>(edge_src, edge_dst, z1, agg1, deg, E);
        k_mid<<<node_grid, BLK, 0, stream>>>(agg1, deg, b1, W2, z2, N);
        k_edge2<<<edge_grid, BLK, 0, stream>>>(edge_src, edge_dst, z2, agg2, E);
        k_out<<<node_grid, BLK, 0, stream>>>(agg2, deg, b2, out, N);
    }
}